// Round 6
// baseline (1219.950 us; speedup 1.0000x reference)
//
#include <hip/hip_runtime.h>
#include <hip/hip_bf16.h>
#include <hip/hip_fp16.h>
#include <stdint.h>

typedef __hip_bfloat16 bf16;
using bf16x8 = __attribute__((ext_vector_type(8))) short;     // 8 bf16
using half8  = __attribute__((ext_vector_type(8))) _Float16;  // 8 fp16
using f32x4  = __attribute__((ext_vector_type(4))) float;

#define S_LEN   4096
#define HID_    2048
#define NH_     16
#define D_      128
#define C_      1024
#define SCALE_  0.08838834764831845f   // 1/sqrt(128)
#define DESC_   (1.0 / 1048576.0)      // 2^-20 (undo ×1024 on both operands)

__device__ __forceinline__ void storeC(float* p, float v) { *p = v; }
__device__ __forceinline__ void storeC(bf16* p, float v)  { *p = __float2bfloat16(v); }
__device__ __forceinline__ void split2(float x, _Float16& h, _Float16& l) {
  h = (_Float16)x; l = (_Float16)(x - (float)h);
}
__device__ __forceinline__ short bf2s(bf16 b) { short s; __builtin_memcpy(&s, &b, 2); return s; }

#define GLDS(src, dst) __builtin_amdgcn_global_load_lds( \
    (const __attribute__((address_space(1))) void*)(src), \
    (__attribute__((address_space(3))) void*)(dst), 16, 0, 0)

// ---------------- fp32 -> bf16 convert (hidden) + bias concat (fused) ----------------
__global__ __launch_bounds__(256) void cvt_bias_k(const float* __restrict__ src, bf16* __restrict__ dst,
                                                  const float* bq, const float* blk, const float* blv,
                                                  const float* bk, const float* bv, const float* bo,
                                                  float* bQ, float* bLKLV, float* bKV, float* bO) {
  int i = (blockIdx.x * 256 + threadIdx.x) * 4;
  float4 v = *(const float4*)(src + i);
  bf16 o[4] = {__float2bfloat16(v.x), __float2bfloat16(v.y),
               __float2bfloat16(v.z), __float2bfloat16(v.w)};
  *(uint2*)(dst + i) = *(uint2*)o;
  int ib = blockIdx.x * 256 + threadIdx.x;
  if (ib < 8448) {
    if (ib < 2048)      bQ[ib] = bq[ib];
    else if (ib < 6144) { int j = ib - 2048; bLKLV[j] = (j < 2048) ? blk[j] : blv[j - 2048]; }
    else if (ib < 6400) { int j = ib - 6144; bKV[j] = (j < 128) ? bk[j] : bv[j - 128]; }
    else                bO[ib - 6400] = bo[ib - 6400];
  }
}

// ---------------- fp32 -> fp16 hi/lo split (x1024), contiguous (hidden pre-split) ----------------
__global__ __launch_bounds__(256) void split_q_k(const float* __restrict__ src,
                                                 _Float16* __restrict__ oh, _Float16* __restrict__ ol) {
  int i = (blockIdx.x * 256 + threadIdx.x) * 4;
  float4 v = *(const float4*)(src + i);
  float xs[4] = {v.x, v.y, v.z, v.w};
  _Float16 hh[4], ll[4];
#pragma unroll
  for (int e = 0; e < 4; ++e) split2(xs[e] * 1024.0f, hh[e], ll[e]);
  *(uint2*)(oh + i) = *(uint2*)hh;
  *(uint2*)(ol + i) = *(uint2*)ll;
}

// ---------------- Wq transpose + x1024 + hi/lo split (fused; replaces trans_f32s + in-gemm split) ----------------
__global__ __launch_bounds__(256) void trans_split_wq(const float* __restrict__ src,
                                                      _Float16* __restrict__ oh, _Float16* __restrict__ ol) {
  __shared__ float tile[64][65];
  const int c0 = blockIdx.x * 64, r0 = blockIdx.y * 64;
  const int t = threadIdx.x, cc = t & 63, rb = t >> 6;
#pragma unroll
  for (int i = 0; i < 16; ++i) {
    int r = rb + i * 4;
    tile[r][cc] = src[(size_t)(r0 + r) * HID_ + c0 + cc];
  }
  __syncthreads();
#pragma unroll
  for (int i = 0; i < 16; ++i) {
    int r = rb + i * 4;
    float x = tile[cc][r] * 1024.0f;           // same value gemm_prec4's B-path saw
    _Float16 h, l; split2(x, h, l);
    size_t off = (size_t)(c0 + r) * HID_ + r0 + cc;
    oh[off] = h; ol[off] = l;
  }
}

// ---------------- 3-way transpose: fp32 (2048x2048) -> bf16 (2048x2048), z selects matrix ----------------
__global__ __launch_bounds__(256) void transpose3_k(const float* __restrict__ Wlk, const float* __restrict__ Wlv,
                                                    const float* __restrict__ Wo,
                                                    bf16* __restrict__ bt_lklv, bf16* __restrict__ WoT) {
  __shared__ float tile[64][65];
  const float* src = (blockIdx.z == 0) ? Wlk : (blockIdx.z == 1) ? Wlv : Wo;
  bf16* dst = (blockIdx.z == 0) ? bt_lklv
            : (blockIdx.z == 1) ? (bt_lklv + (size_t)2048 * HID_) : WoT;
  const int c0 = blockIdx.x * 64, r0 = blockIdx.y * 64;
  const int t = threadIdx.x, cc = t & 63, rb = t >> 6;
#pragma unroll
  for (int i = 0; i < 16; ++i) {
    int r = rb + i * 4;
    tile[r][cc] = src[(size_t)(r0 + r) * HID_ + c0 + cc];
  }
  __syncthreads();
#pragma unroll
  for (int i = 0; i < 16; ++i) {
    int r = rb + i * 4;
    dst[(size_t)(c0 + r) * HID_ + r0 + cc] = __float2bfloat16(tile[cc][r]);
  }
}

// ---------------- Wk/Wv transpose + x1024 (z selects) ----------------
__global__ __launch_bounds__(256) void trans_f32s_kv(const float* __restrict__ Wk, const float* __restrict__ Wv,
                                                     float* __restrict__ WkvTs) {
  __shared__ float tile[64][65];
  const float* src = blockIdx.z ? Wv : Wk;
  float* dst = WkvTs + (blockIdx.z ? (size_t)128 * HID_ : 0);
  const int c0 = blockIdx.x * 64, r0 = blockIdx.y * 64;
  const int t = threadIdx.x, cc = t & 63, rb = t >> 6;
#pragma unroll
  for (int i = 0; i < 16; ++i) {
    int r = rb + i * 4;
    tile[r][cc] = src[(size_t)(r0 + r) * 128 + c0 + cc];
  }
  __syncthreads();
#pragma unroll
  for (int i = 0; i < 16; ++i) {
    int r = rb + i * 4;
    dst[(size_t)(c0 + r) * HID_ + r0 + cc] = tile[cc][r] * 1024.0f;
  }
}

// ---------------- transpose lv half of lklv (bf16 [4096][2048-slice]) -> VT [2048][4096] ----------------
__global__ __launch_bounds__(256) void trans_v_k(const bf16* __restrict__ lklv, bf16* __restrict__ VT) {
  __shared__ ushort tile[64][65];
  const int s0 = blockIdx.x * 64, c0 = blockIdx.y * 64;
  const int t = threadIdx.x, cc = t & 63, rb = t >> 6;
  const ushort* src = (const ushort*)lklv;
#pragma unroll
  for (int i = 0; i < 16; ++i) {
    int r = rb + i * 4;
    tile[r][cc] = src[(size_t)(s0 + r) * 4096 + 2048 + c0 + cc];
  }
  __syncthreads();
  ushort* dst = (ushort*)VT;
#pragma unroll
  for (int i = 0; i < 16; ++i) {
    int r = rb + i * 4;
    dst[(size_t)(c0 + r) * 4096 + s0 + cc] = tile[cc][r];
  }
}

// ---------------- plain m97-style bf16 GEMM ----------------
template <typename OutT>
__global__ __launch_bounds__(256) void gemm_bt(const bf16* __restrict__ A, const bf16* __restrict__ BT,
                                               const float* __restrict__ bias, OutT* __restrict__ Cmat,
                                               int M, int N, int K, int lda) {
  __shared__ bf16 As[128 * 32];
  __shared__ bf16 Bs[128 * 32];
  const int t = threadIdx.x;
  const int wave = t >> 6, lane = t & 63;
  const int wr = wave >> 1, wc = wave & 1;
  const int quad = lane >> 4, l15 = lane & 15;
  const int bx = blockIdx.x * 128, by = blockIdx.y * 128;
  const int srow = t >> 2, scol = (t & 3) * 8;
  f32x4 acc[4][4] = {};
  const bf16* a0 = A + (size_t)(by + srow) * lda + scol;
  const bf16* a1 = A + (size_t)(by + 64 + srow) * lda + scol;
  const bf16* b0 = BT + (size_t)(bx + srow) * K + scol;
  const bf16* b1 = BT + (size_t)(bx + 64 + srow) * K + scol;
  for (int k0 = 0; k0 < K; k0 += 32) {
    GLDS(a0 + k0, As + t * 8);
    GLDS(a1 + k0, As + 2048 + t * 8);
    GLDS(b0 + k0, Bs + t * 8);
    GLDS(b1 + k0, Bs + 2048 + t * 8);
    __syncthreads();
    bf16x8 aF[4], bF[4];
#pragma unroll
    for (int i = 0; i < 4; ++i)
      aF[i] = *(const bf16x8*)(As + (wr * 64 + i * 16 + l15) * 32 + quad * 8);
#pragma unroll
    for (int j = 0; j < 4; ++j)
      bF[j] = *(const bf16x8*)(Bs + (wc * 64 + j * 16 + l15) * 32 + quad * 8);
#pragma unroll
    for (int i = 0; i < 4; ++i)
#pragma unroll
      for (int j = 0; j < 4; ++j)
        acc[i][j] = __builtin_amdgcn_mfma_f32_16x16x32_bf16(aF[i], bF[j], acc[i][j], 0, 0, 0);
    __syncthreads();
  }
#pragma unroll
  for (int i = 0; i < 4; ++i)
#pragma unroll
    for (int j = 0; j < 4; ++j)
#pragma unroll
      for (int r = 0; r < 4; ++r) {
        int row = by + wr * 64 + i * 16 + quad * 4 + r;
        int col = bx + wc * 64 + j * 16 + l15;
        storeC(&Cmat[(size_t)row * N + col], acc[i][j][r] + bias[col]);
      }
}

// ---------------- precise GEMM, pre-split operands + global_load_lds staging ----------------
// Bit-identical arithmetic to gemm_prec4 (same MFMA 4-chain order, same per-kstep fp64 accum),
// but operands arrive pre-split (no in-loop VALU staging).
__global__ __launch_bounds__(256) void gemm_hl4(const _Float16* __restrict__ Ah, const _Float16* __restrict__ Al,
                                                const _Float16* __restrict__ Bh, const _Float16* __restrict__ Bl,
                                                const float* __restrict__ bias, float* __restrict__ Cmat,
                                                int M, int N, int K, int lda) {
  __shared__ _Float16 Ahs[128 * 32], Als[128 * 32], Bhs[128 * 32], Bls[128 * 32];
  const int t = threadIdx.x;
  const int wave = t >> 6, lane = t & 63;
  const int wr = wave >> 1, wc = wave & 1;
  const int quad = lane >> 4, l15 = lane & 15;
  const int bx = blockIdx.x * 128, by = blockIdx.y * 128;
  const int srow = t >> 2, scol = (t & 3) * 8;
  double acc[4][4][4] = {};
  const _Float16* a0h = Ah + (size_t)(by + srow) * lda + scol;
  const _Float16* a1h = Ah + (size_t)(by + 64 + srow) * lda + scol;
  const _Float16* a0l = Al + (size_t)(by + srow) * lda + scol;
  const _Float16* a1l = Al + (size_t)(by + 64 + srow) * lda + scol;
  const _Float16* b0h = Bh + (size_t)(bx + srow) * K + scol;
  const _Float16* b1h = Bh + (size_t)(bx + 64 + srow) * K + scol;
  const _Float16* b0l = Bl + (size_t)(bx + srow) * K + scol;
  const _Float16* b1l = Bl + (size_t)(bx + 64 + srow) * K + scol;
  for (int k0 = 0; k0 < K; k0 += 32) {
    GLDS(a0h + k0, Ahs + t * 8);
    GLDS(a1h + k0, Ahs + 2048 + t * 8);
    GLDS(a0l + k0, Als + t * 8);
    GLDS(a1l + k0, Als + 2048 + t * 8);
    GLDS(b0h + k0, Bhs + t * 8);
    GLDS(b1h + k0, Bhs + 2048 + t * 8);
    GLDS(b0l + k0, Bls + t * 8);
    GLDS(b1l + k0, Bls + 2048 + t * 8);
    __syncthreads();
    half8 aFh[4], aFl[4], bFh[4], bFl[4];
#pragma unroll
    for (int i = 0; i < 4; ++i) {
      int ro = (wr * 64 + i * 16 + l15) * 32 + quad * 8;
      aFh[i] = *(const half8*)(Ahs + ro);
      aFl[i] = *(const half8*)(Als + ro);
    }
#pragma unroll
    for (int j = 0; j < 4; ++j) {
      int ro = (wc * 64 + j * 16 + l15) * 32 + quad * 8;
      bFh[j] = *(const half8*)(Bhs + ro);
      bFl[j] = *(const half8*)(Bls + ro);
    }
#pragma unroll
    for (int i = 0; i < 4; ++i)
#pragma unroll
      for (int j = 0; j < 4; ++j) {
        f32x4 tt = {0.f, 0.f, 0.f, 0.f};
        tt = __builtin_amdgcn_mfma_f32_16x16x32_f16(aFl[i], bFl[j], tt, 0, 0, 0);
        tt = __builtin_amdgcn_mfma_f32_16x16x32_f16(aFl[i], bFh[j], tt, 0, 0, 0);
        tt = __builtin_amdgcn_mfma_f32_16x16x32_f16(aFh[i], bFl[j], tt, 0, 0, 0);
        tt = __builtin_amdgcn_mfma_f32_16x16x32_f16(aFh[i], bFh[j], tt, 0, 0, 0);
#pragma unroll
        for (int r = 0; r < 4; ++r) acc[i][j][r] += (double)tt[r];
      }
    __syncthreads();
  }
#pragma unroll
  for (int i = 0; i < 4; ++i)
#pragma unroll
    for (int j = 0; j < 4; ++j)
#pragma unroll
      for (int r = 0; r < 4; ++r) {
        int row = by + wr * 64 + i * 16 + quad * 4 + r;
        int col = bx + wc * 64 + j * 16 + l15;
        Cmat[(size_t)row * N + col] = (float)(acc[i][j][r] * DESC_ + (double)bias[col]);
      }
}

// ---------------- precise GEMM with in-kernel split (kept for small ckv projection) ----------------
__global__ __launch_bounds__(256) void gemm_prec4(const float* __restrict__ A, const float* __restrict__ BT,
                                                  const float* __restrict__ bias, float* __restrict__ Cmat,
                                                  int M, int N, int K, int lda) {
  __shared__ _Float16 Ah[128 * 32], Al[128 * 32], Bh[128 * 32], Bl[128 * 32];
  const int t = threadIdx.x;
  const int wave = t >> 6, lane = t & 63;
  const int wr = wave >> 1, wc = wave & 1;
  const int quad = lane >> 4, l15 = lane & 15;
  const int bx = blockIdx.x * 128, by = blockIdx.y * 128;
  double acc[4][4][4] = {};
  for (int k0 = 0; k0 < K; k0 += 32) {
#pragma unroll
    for (int it = 0; it < 4; ++it) {
      int sl = t + it * 256;
      int isB = sl >> 9, s2 = sl & 511, r = s2 >> 2, g = s2 & 3;
      const float* src = isB ? (BT + (size_t)(bx + r) * K + k0 + g * 8)
                             : (A  + (size_t)(by + r) * lda + k0 + g * 8);
      float4 u = ((const float4*)src)[0];
      float4 v = ((const float4*)src)[1];
      float xs[8] = {u.x, u.y, u.z, u.w, v.x, v.y, v.z, v.w};
      half8 hh, ll;
#pragma unroll
      for (int e = 0; e < 8; ++e) {
        float x = isB ? xs[e] : xs[e] * 1024.0f;
        _Float16 h, l; split2(x, h, l);
        hh[e] = h; ll[e] = l;
      }
      _Float16* dh = (isB ? Bh : Ah) + r * 32 + g * 8;
      _Float16* dl = (isB ? Bl : Al) + r * 32 + g * 8;
      *(half8*)dh = hh;
      *(half8*)dl = ll;
    }
    __syncthreads();
    half8 aFh[4], aFl[4], bFh[4], bFl[4];
#pragma unroll
    for (int i = 0; i < 4; ++i) {
      int ro = (wr * 64 + i * 16 + l15) * 32 + quad * 8;
      aFh[i] = *(const half8*)(Ah + ro);
      aFl[i] = *(const half8*)(Al + ro);
    }
#pragma unroll
    for (int j = 0; j < 4; ++j) {
      int ro = (wc * 64 + j * 16 + l15) * 32 + quad * 8;
      bFh[j] = *(const half8*)(Bh + ro);
      bFl[j] = *(const half8*)(Bl + ro);
    }
#pragma unroll
    for (int i = 0; i < 4; ++i)
#pragma unroll
      for (int j = 0; j < 4; ++j) {
        f32x4 tt = {0.f, 0.f, 0.f, 0.f};
        tt = __builtin_amdgcn_mfma_f32_16x16x32_f16(aFl[i], bFl[j], tt, 0, 0, 0);
        tt = __builtin_amdgcn_mfma_f32_16x16x32_f16(aFl[i], bFh[j], tt, 0, 0, 0);
        tt = __builtin_amdgcn_mfma_f32_16x16x32_f16(aFh[i], bFl[j], tt, 0, 0, 0);
        tt = __builtin_amdgcn_mfma_f32_16x16x32_f16(aFh[i], bFh[j], tt, 0, 0, 0);
#pragma unroll
        for (int r = 0; r < 4; ++r) acc[i][j][r] += (double)tt[r];
      }
    __syncthreads();
  }
#pragma unroll
  for (int i = 0; i < 4; ++i)
#pragma unroll
    for (int j = 0; j < 4; ++j)
#pragma unroll
      for (int r = 0; r < 4; ++r) {
        int row = by + wr * 64 + i * 16 + quad * 4 + r;
        int col = bx + wc * 64 + j * 16 + l15;
        Cmat[(size_t)row * N + col] = (float)(acc[i][j][r] * DESC_ + (double)bias[col]);
      }
}

// ---------------- fp64 rmsnorm + rope for q: one block per s, trig shared across 16 heads ----------------
__global__ __launch_bounds__(256) void normrope64_q(float* __restrict__ base, const float* __restrict__ w,
                                                    _Float16* __restrict__ qh, _Float16* __restrict__ ql) {
  __shared__ double csd[32], snd[32];
  const int s = blockIdx.x;
  const int t = threadIdx.x, wv = t >> 6, lane = t & 63;
  if (t < 32) {
    float invf = 1.0f / (float)pow(10000.0, (double)t * (1.0 / 32.0));
    float angf = (float)s * invf;
    double ang = (double)angf;
    csd[t] = cos(ang);
    snd[t] = sin(ang);
  }
  __syncthreads();
  const int fi = lane & 31;
  float* ps = base + (size_t)s * HID_;
  for (int h = wv; h < 16; h += 4) {
    float* p = ps + h * 128;
    double x0 = (double)p[lane];
    double x1 = (double)p[lane + 64];
    double ss = x0 * x0 + x1 * x1;
#pragma unroll
    for (int m = 32; m; m >>= 1) ss += __shfl_xor(ss, m, 64);
    double rstd = 1.0 / sqrt(ss * (1.0 / 128.0) + 1e-6);
    double n0 = x0 * rstd * (double)w[lane];
    double n1 = x1 * rstd * (double)w[lane + 64];
    double other = __shfl_xor(n0, 32, 64);
    double cs = csd[fi], sn = snd[fi];
    double r0 = (lane < 32) ? (n0 * cs - other * sn) : (other * sn + n0 * cs);
    float f0 = (float)r0, f1 = (float)n1;
    p[lane] = f0;
    p[lane + 64] = f1;
    _Float16 h0, l0, h1, l1;
    split2(f0 * 1024.0f, h0, l0);
    split2(f1 * 1024.0f, h1, l1);
    size_t off = (size_t)s * HID_ + h * 128;
    qh[off + lane] = h0;       ql[off + lane] = l0;
    qh[off + 64 + lane] = h1;  ql[off + 64 + lane] = l1;
  }
}

// ---------------- fp64 rmsnorm + rope for ckv rows + fused fp16 hi/lo split ----------------
__global__ __launch_bounds__(256) void normrope64_ck(float* __restrict__ base, const float* __restrict__ w,
                                                     _Float16* __restrict__ ckh, _Float16* __restrict__ ckl) {
  int row = blockIdx.x * 4 + (threadIdx.x >> 6);   // grid 256 -> rows 0..1023
  int lane = threadIdx.x & 63;
  float* p = base + (size_t)row * 256;
  double x0 = (double)p[lane];
  double x1 = (double)p[lane + 64];
  double ss = x0 * x0 + x1 * x1;
#pragma unroll
  for (int m = 32; m; m >>= 1) ss += __shfl_xor(ss, m, 64);
  double rstd = 1.0 / sqrt(ss * (1.0 / 128.0) + 1e-6);
  double n0 = x0 * rstd * (double)w[lane];
  double n1 = x1 * rstd * (double)w[lane + 64];
  double other = __shfl_xor(n0, 32, 64);
  int fi = lane & 31;
  float invf = 1.0f / (float)pow(10000.0, (double)fi * (1.0 / 32.0));
  float angf = (float)(row * 4 + 3) * invf;
  double ang = (double)angf;
  double cs = cos(ang), sn = sin(ang);
  double r0 = (lane < 32) ? (n0 * cs - other * sn) : (other * sn + n0 * cs);
  float f0 = (float)r0, f1 = (float)n1;
  p[lane] = f0;
  p[lane + 64] = f1;
  _Float16 h0, l0, h1, l1;                          // identical to old split_ck_k on stored values
  split2(f0 * 1024.0f, h0, l0);
  split2(f1 * 1024.0f, h1, l1);
  ckh[row * 128 + lane] = h0;       ckl[row * 128 + lane] = l0;
  ckh[row * 128 + 64 + lane] = h1;  ckl[row * 128 + 64 + lane] = l1;
}

// ---------------- bf16 rmsnorm+rope for lk: one block per s, trig shared across 16 heads ----------------
__global__ __launch_bounds__(256) void normrope_bf_l(bf16* __restrict__ base, const float* __restrict__ w) {
  __shared__ float csf[32], snf[32];
  const int s = blockIdx.x;
  const int t = threadIdx.x, wv = t >> 6, lane = t & 63;
  if (t < 32) {
    float invf = 1.0f / (float)pow(10000.0, (double)t * (1.0 / 32.0));
    float ang = (float)s * invf;
    csf[t] = cosf(ang);
    snf[t] = sinf(ang);
  }
  __syncthreads();
  const int fi = lane & 31;
  bf16* ps = base + (size_t)s * 4096;
  for (int h = wv; h < 16; h += 4) {
    bf16* p = ps + h * 128;
    float x0 = __bfloat162float(p[lane]);
    float x1 = __bfloat162float(p[lane + 64]);
    float ss = x0 * x0 + x1 * x1;
#pragma unroll
    for (int m = 32; m; m >>= 1) ss += __shfl_xor(ss, m, 64);
    float rstd = rsqrtf(ss * 0.0078125f + 1e-6f);
    float n0 = x0 * rstd * w[lane];
    float n1 = x1 * rstd * w[lane + 64];
    float other = __shfl_xor(n0, 32, 64);
    float cs = csf[fi], sn = snf[fi];
    float r0 = (lane < 32) ? (n0 * cs - other * sn) : (other * sn + n0 * cs);
    p[lane] = __float2bfloat16(r0);
    p[lane + 64] = __float2bfloat16(n1);
  }
}

// ---------------- compress logits (fp64) ----------------
__global__ __launch_bounds__(256) void wlog_k(const float* __restrict__ hidden, const float* __restrict__ wcmp,
                                              const float* __restrict__ bcmp, float* __restrict__ wlog) {
  int s = blockIdx.x * 4 + (threadIdx.x >> 6);
  int lane = threadIdx.x & 63;
  const float* hp = hidden + (size_t)s * HID_;
  double acc = 0.0;
  for (int i = lane; i < HID_; i += 64)
    acc += (double)hp[i] * (double)wcmp[i];
#pragma unroll
  for (int m = 32; m; m >>= 1) acc += __shfl_xor(acc, m, 64);
  if (lane == 0) wlog[s] = (float)(acc + (double)bcmp[0]);
}

__global__ void wsm_k(const float* __restrict__ wlog, float* __restrict__ wsm) {
  int c = blockIdx.x * 256 + threadIdx.x;
  if (c >= C_) return;
  double v[4], m = -1e300;
#pragma unroll
  for (int r = 0; r < 4; ++r) { v[r] = (double)wlog[4 * c + r]; if (v[r] > m) m = v[r]; }
  double sum = 0.0;
#pragma unroll
  for (int r = 0; r < 4; ++r) { v[r] = exp(v[r] - m); sum += v[r]; }
#pragma unroll
  for (int r = 0; r < 4; ++r) wsm[4 * c + r] = (float)(v[r] / sum);
}

__global__ __launch_bounds__(256) void entries_k(const float* __restrict__ hidden, const float* __restrict__ wsm,
                                                 float* __restrict__ entriesF) {
  int idx = blockIdx.x * 256 + threadIdx.x;     // c*2048 + hcol
  int c = idx >> 11, hcol = idx & 2047;
  double e = 0.0;
#pragma unroll
  for (int r = 0; r < 4; ++r)
    e += (double)wsm[4 * c + r] * (double)hidden[(size_t)(4 * c + r) * HID_ + hcol];
  entriesF[idx] = (float)e;
}

// ---------------- sparse v10: phase-1 two-tile ILP; phase-2 stride-16 lane map ----------------
// Phase 1: each wave processes tiles ct and ct+16 with independent accumulators (per-tile
// arithmetic bit-identical to v9). Phase 2: candidate c = j*64 + e*16 + l15 so adjacent
// top-k candidates land on different lanes (rare cache rebuilds). Selection semantics
// unchanged: max value, lowest index on ties, stable ascending scan.
__global__ __launch_bounds__(1024, 8) void sparse_v10(const _Float16* __restrict__ qh, const _Float16* __restrict__ ql,
                                                      const _Float16* __restrict__ ckh, const _Float16* __restrict__ ckl,
                                                      const float* __restrict__ ckvF, bf16* __restrict__ sp) {
  __shared__ float sc[16 * 1024];               // 64 KB -> 2 blocks/CU
  const int by = blockIdx.y;                    // head pair: heads 2*by, 2*by+1
  const int s0 = blockIdx.x * 8;
  const int t = threadIdx.x, w = t >> 6, lane = t & 63;
  const int quad = lane >> 4, l15 = lane & 15;
  const int nvmax  = (s0 >> 2) + 2;
  const int ntiles = (nvmax + 15) >> 4;
  const double esc = (double)SCALE_ * DESC_;

  if (w < ntiles) {
    const int sA = s0 + (l15 & 7);
    const int hA = 2 * by + (l15 >> 3);
    half8 aFh[4], aFl[4];
    {
      const _Float16* qbh = qh + (size_t)sA * HID_ + hA * 128 + quad * 8;
      const _Float16* qbl = ql + (size_t)sA * HID_ + hA * 128 + quad * 8;
#pragma unroll
      for (int kk = 0; kk < 4; ++kk) {
        aFh[kk] = *(const half8*)(qbh + kk * 32);
        aFl[kk] = *(const half8*)(qbl + kk * 32);
      }
    }
    for (int ct = w; ct < ntiles; ct += 32) {
      const int c0a = ct * 16;
      const bool two = (ct + 16) < ntiles;
      const int c0b = two ? (ct + 16) * 16 : c0a;   // clamp: dummy work, not stored
      const _Float16* kbha = ckh + (size_t)(c0a + l15) * 128 + quad * 8;
      const _Float16* kbla = ckl + (size_t)(c0a + l15) * 128 + quad * 8;
      const _Float16* kbhb = ckh + (size_t)(c0b + l15) * 128 + quad * 8;
      const _Float16* kblb = ckl + (size_t)(c0b + l15) * 128 + quad * 8;
      double a64a[4] = {0.0, 0.0, 0.0, 0.0};
      double a64b[4] = {0.0, 0.0, 0.0, 0.0};
#pragma unroll
      for (int kk = 0; kk < 4; ++kk) {
        half8 bha = *(const half8*)(kbha + kk * 32);
        half8 bla = *(const half8*)(kbla + kk * 32);
        half8 bhb = *(const half8*)(kbhb + kk * 32);
        half8 blb = *(const half8*)(kblb + kk * 32);
        f32x4 tta = {0.f, 0.f, 0.f, 0.f};
        tta = __builtin_amdgcn_mfma_f32_16x16x32_f16(aFl[kk], bla, tta, 0, 0, 0);
        tta = __builtin_amdgcn_mfma_f32_16x16x32_f16(aFl[kk], bha, tta, 0, 0, 0);
        tta = __builtin_amdgcn_mfma_f32_16x16x32_f16(aFh[kk], bla, tta, 0, 0, 0);
        tta = __builtin_amdgcn_mfma_f32_16x16x32_f16(aFh[kk], bha, tta, 0, 0, 0);
        f32x4 ttb = {0.f, 0.f, 0.f, 0.f};
        ttb = __builtin_amdgcn_mfma_f32_16x16x32_f16(aFl[kk], blb, ttb, 0, 0, 0);
        ttb = __builtin_amdgcn_mfma_f32_16x16x32_f16(aFl[kk], bhb, ttb, 0, 0, 0);
        ttb = __builtin_amdgcn_mfma_f32_16x16x32_f16(aFh[kk], blb, ttb, 0, 0, 0);
        ttb = __builtin_amdgcn_mfma_f32_16x16x32_f16(aFh[kk], bhb, ttb, 0, 0, 0);
#pragma unroll
        for (int r = 0; r < 4; ++r) { a64a[r] += (double)tta[r]; a64b[r] += (double)ttb[r]; }
      }
#pragma unroll
      for (int r = 0; r < 4; ++r)
        sc[(quad * 4 + r) * 1024 + c0a + l15] = (float)(a64a[r] * esc);
      if (two) {
#pragma unroll
        for (int r = 0; r < 4; ++r)
          sc[(quad * 4 + r) * 1024 + c0b + l15] = (float)(a64b[r] * esc);
      }
    }
  }
  __syncthreads();
  if (w >= 4) return;

  // ---- phase 2: chain q = w*4 + quad, handled by 16 lanes (l15) ----
  const int q = w * 4 + quad;
  const int p2 = q >> 3, wq = q & 7;
  const int s = s0 + wq;
  const int nv = (s >= 3) ? (((s - 3) >> 2) + 1) : 0;
  const float* srowL = sc + q * 1024 + l15;
  const int jmaxB = (nvmax + 63) >> 6;

  // per-lane top-4 cache over candidates c = j*64 + e*16 + l15 (ascending c per lane)
  float tv0 = -1e38f, tv1 = -1e38f, tv2 = -1e38f, tv3 = -1e38f;
  int   ti0 = 0x40000000, ti1 = 0x40000000, ti2 = 0x40000000, ti3 = 0x40000000;
  for (int j = 0; j < jmaxB; ++j) {
    int base = j * 64;
#pragma unroll
    for (int e = 0; e < 4; ++e) {
      int c = base + e * 16 + l15;
      float v = (c < nv) ? srowL[base + e * 16] : -1e38f;
      if (v > tv3) {
        if (v > tv0)      { tv3=tv2;ti3=ti2; tv2=tv1;ti2=ti1; tv1=tv0;ti1=ti0; tv0=v;ti0=c; }
        else if (v > tv1) { tv3=tv2;ti3=ti2; tv2=tv1;ti2=ti1; tv1=v;ti1=c; }
        else if (v > tv2) { tv3=tv2;ti3=ti2; tv2=v;ti2=c; }
        else              { tv3=v;ti3=c; }
      }
    }
  }

  unsigned long long deadm = 0ull;
  int ncons = 0;
  float bvs[8]; int bis[8];
#pragma unroll
  for (int it = 0; it < 8; ++it) {
    float bv = tv0; int bi = ti0;
#pragma unroll
    for (int mm = 1; mm <= 8; mm <<= 1) {
      float ov = __shfl_xor(bv, mm, 64);
      int   oi = __shfl_xor(bi, mm, 64);
      if (ov > bv || (ov == bv && oi < bi)) { bv = ov; bi = oi; }
    }
    bvs[it] = bv; bis[it] = bi;
    if (bv > -1e29f && ((bi & 15) == l15)) {      // this lane owned the winner
      deadm |= 1ull << (((bi >> 6) << 2) | ((bi >> 4) & 3));
      tv0=tv1;ti0=ti1; tv1=tv2;ti1=ti2; tv2=tv3;ti2=ti3;
      tv3=-1e38f; ti3=0x40000000;
      if (++ncons == 4) {                          // cache exhausted: rebuild (rare)
        ncons = 0;
        tv0=tv1=tv2=tv3=-1e38f;
        ti0=ti1=ti2=ti3=0x40000000;
        for (int j = 0; j < jmaxB; ++j) {
          int base = j * 64;
#pragma unroll
          for (int e = 0; e < 4; ++e) {
            int c = base + e * 16 + l15;
            int li = (j << 2) | e;
            float v = (c < nv && !((deadm >> li) & 1ull)) ? srowL[base + e * 16] : -1e38f;
            if (v > tv3) {
              if (v > tv0)      { tv3=tv2;ti3=ti2; tv2=tv1;ti2=ti1; tv1=tv0;ti1=ti0; tv0=v;ti0=c; }
              else if (v > tv1) { tv3=tv2;ti3=ti2; tv2=tv1;ti2=ti1; tv1=v;ti1=c; }
              else if (v > tv2) { tv3=tv2;ti3=ti2; tv2=v;ti2=c; }
              else              { tv3=v;ti3=c; }
            }
          }
        }
      }
    }
  }

  // ---- gathers + softmax + output (16 lanes x 8 floats = 128 dims) ----
  const float m0 = bvs[0];
  float a0=0.f,a1=0.f,a2=0.f,a3=0.f,a4=0.f,a5=0.f,a6=0.f,a7=0.f;
  float esum = 0.f;
#pragma unroll
  for (int it = 0; it < 8; ++it) {
    if (bvs[it] > -1e29f) {
      float wgt = expf(bvs[it] - m0);
      esum += wgt;
      const float* cvp = ckvF + (size_t)bis[it] * 256 + 128 + l15 * 8;
      float4 u = *(const float4*)cvp;
      float4 v = *(const float4*)(cvp + 4);
      a0 += wgt*u.x; a1 += wgt*u.y; a2 += wgt*u.z; a3 += wgt*u.w;
      a4 += wgt*v.x; a5 += wgt*v.y; a6 += wgt*v.z; a7 += wgt*v.w;
    }
  }
  float inv = 1.0f / fmaxf(esum, 1e-9f);
  bf16* op = sp + (size_t)s * 2048 + (2 * by + p2) * 128 + l15 * 8;
  bf16 ob[8] = {__float2bfloat16(a0*inv), __float2bfloat16(a1*inv),
                __float2bfloat16(a2*inv), __float2bfloat16(a3*inv),
                __float2bfloat16(a4*inv), __float2bfloat16(a5*inv),
                __float2bfloat16(a6*inv), __float2bfloat16(a7*inv)};
  *(uint4*)op = *(uint4*)ob;
}

// ---------------- local sliding-window via MFMA ----------------
__global__ __launch_bounds__(128) void local_mfma(const float* __restrict__ qf,
                                                  const bf16* __restrict__ lklv,
                                                  const bf16* __restrict__ VT,
                                                  const bf16* __restrict__ sp,
                                                  bf16* __restrict__ merged) {
  constexpr int PADP = 168;
  __shared__ bf16 PhS[2][16 * PADP];
  __shared__ bf16 PlS[2][16 * PADP];
  const int h = blockIdx.y;
  const int t = threadIdx.x, w = t >> 6, lane = t & 63;
  const int quad = lane >> 4, l15 = lane & 15;
  const int sw = blockIdx.x * 32 + w * 16;
  const int kbase = sw - 128;
  const int ridx = quad * 4;

  bf16x8 qH[4], qL[4];
  {
    const float* qp = qf + (size_t)(sw + l15) * HID_ + h * 128 + quad * 8;
#pragma unroll
    for (int kk = 0; kk < 4; ++kk) {
      float4 u = *(const float4*)(qp + kk * 32);
      float4 v = *(const float4*)(qp + kk * 32 + 4);
      float xs[8] = {u.x, u.y, u.z, u.w, v.x, v.y, v.z, v.w};
      bf16x8 hh, ll;
#pragma unroll
      for (int e = 0; e < 8; ++e) {
        bf16 bh = __float2bfloat16(xs[e]);
        float fh = __bfloat162float(bh);
        bf16 bl = __float2bfloat16(xs[e] - fh);
        hh[e] = bf2s(bh); ll[e] = bf2s(bl);
      }
      qH[kk] = hh; qL[kk] = ll;
    }
  }

  float sc[9][4];
#pragma unroll
  for (int ct = 0; ct < 9; ++ct) {
    int key0 = kbase + ct * 16 + l15;
    const bf16* kp = lklv + (size_t)(key0 < 0 ? 0 : key0) * 4096 + h * 128 + quad * 8;
    f32x4 acc = {0.f, 0.f, 0.f, 0.f};
#pragma unroll
    for (int kk = 0; kk < 4; ++kk) {
      bf16x8 kb = *(const bf16x8*)(kp + kk * 32);
      acc = __builtin_amdgcn_mfma_f32_16x16x32_bf16(qL[kk], kb, acc, 0, 0, 0);
      acc = __builtin_amdgcn_mfma_f32_16x16x32_bf16(qH[kk], kb, acc, 0, 0, 0);
    }
#pragma unroll
    for (int r = 0; r < 4; ++r) sc[ct][r] = acc[r] * SCALE_;
  }

  float mrow[4] = {-1e30f, -1e30f, -1e30f, -1e30f};
#pragma unroll
  for (int ct = 0; ct < 9; ++ct) {
    int cidx = ct * 16 + l15;
#pragma unroll
    for (int r = 0; r < 4; ++r) {
      bool valid = (cidx >= ridx + r) && (cidx <= ridx + r + 128) && (kbase + cidx >= 0);
      float v = valid ? sc[ct][r] : -1e30f;
      sc[ct][r] = v;
      mrow[r] = fmaxf(mrow[r], v);
    }
  }
#pragma unroll
  for (int mm = 1; mm <= 8; mm <<= 1)
#pragma unroll
    for (int r = 0; r < 4; ++r) mrow[r] = fmaxf(mrow[r], __shfl_xor(mrow[r], mm, 64));

  bf16* phb = &PhS[w][0];
  bf16* plb = &PlS[w][0];
  for (int z = lane; z < 256; z += 64) {
    int zr = z >> 4, zc = z & 15;
    phb[zr * PADP + 144 + zc] = __float2bfloat16(0.f);
    plb[zr * PADP + 144 + zc] = __float2bfloat16(0.f);
  }
  float lsum[4] = {0.f, 0.f, 0.f, 0.f};
#pragma unroll
  for (int ct = 0; ct < 9; ++ct) {
    int cidx = ct * 16 + l15;
#pragma unroll
    for (int r = 0; r < 4; ++r) {
      float e = (sc[ct][r] > -1e29f) ? expf(sc[ct][r] - mrow[r]) : 0.f;
      lsum[r] += e;
      bf16 bh = __float2bfloat16(e);
      float fh = __bfloat162float(bh);
      bf16 bl = __float2bfloat16(e - fh);
      phb[(ridx + r) * PADP + cidx] = bh;
      plb[(ridx + r) * PADP + cidx] = bl;
    }
  }
#pragma unroll
  for (int mm = 1; mm <= 8; mm <<= 1)
#pragma unroll
    for (int r = 0; r < 4; ++r) lsum[r] += __shfl_xor(lsum[r], mm, 64);
  float inv[4];
#pragma unroll
  for (int r = 0; r < 4; ++r) inv[r] = 1.0f / lsum[r];

  bf16x8 pH[5], pL[5];
#pragma unroll
  for (int kk = 0; kk < 5; ++kk) {
    pH[kk] = *(const bf16x8*)(phb + l15 * PADP + kk * 32 + quad * 8);
    pL[kk] = *(const bf16x8*)(plb + l15 * PADP + kk * 32 + quad * 8);
  }

#pragma unroll
  for (int dt = 0; dt < 8; ++dt) {
    const bf16* vrow = VT + (size_t)(h * 128 + dt * 16 + l15) * 4096;
    f32x4 acc = {0.f, 0.f, 0.f, 0.f};
#pragma unroll
    for (int kk = 0; kk < 5; ++kk) {
      int ko = kbase + kk * 32 + quad * 8;
      ko = ko < 0 ? 0 : (ko > 4088 ? 4088 : ko);
      bf16x8 vb = *(const bf16x8*)(vrow + ko);
      acc = __builtin_amdgcn_mfma_f32_16x16x32_bf16(pL[kk], vb, acc, 0, 0, 0);
      acc = __builtin_amdgcn_mfma_f32_16x16x32_bf16(pH[kk], vb, acc, 0, 0, 0);
    }
#pragma unroll
    for (int r = 0; r < 4; ++r) {
      int srow = sw + ridx + r;
      size_t off = (size_t)srow * 2048 + h * 128 + dt * 16 + l15;
      float spv = __bfloat162float(sp[off]);
      merged[off] = __float2bfloat16((acc[r] * inv[r] + spv) * 0.5f);
    }
  }
}

// ---------------- host orchestration ----------------
extern "C" void kernel_launch(void* const* d_in, const int* in_sizes, int n_in,
                              void* d_out, int out_size, void* d_ws, size_t ws_size,
                              hipStream_t stream) {
  (void)in_sizes; (void)n_in; (void)out_size; (void)ws_size;
  const float* hidden = (const float*)d_in[0];
  const float* Wq   = (const float*)d_in[1];
  const float* bq   = (const float*)d_in[2];
  const float* Wcmp = (const float*)d_in[3];
  const float* bcmp = (const float*)d_in[4];
  const float* Wk   = (const float*)d_in[5];
  const float* bk   = (const float*)d_in[6];
  const float* Wv   = (const float*)d_in[7];
  const float* bv   = (const float*)d_in[8];
  const float* Wlk  = (const float*)d_in[9];
  const float* blk  = (const float*)d_in[10];
  const float* Wlv  = (const float*)d_in[11];
  const float* blv  = (const float*)d_in[12];
  const float* qn_w = (const float*)d_in[13];
  const float* kn_w = (const float*)d_in[14];
  const float* Wo   = (const float*)d_in[15];
  const float* bo   = (const float*)d_in[16];
  float* out = (float*)d_out;

  // workspace (~155 MB). Overlay timeline (all same-stream, serial):
  //  region A (67108864, 16.7M): qh (normrope_q..sparse) -> VT (trans_v..local)
  //  region B (83886080, 16.7M): hbf (cvt..lklv-gemm) -> hidh (split..gemm_hl4) -> merged (local..out-gemm)
  //  region C (100663296,16.7M): bt_lklv (transpose3..lklv-gemm) -> hidl (split..gemm_hl4) -> sp (sparse..local)
  //  region D (137954304,16.7M): wqh|wql (trans_split..gemm_hl4) -> ql (normrope_q..sparse)
  char* ws = (char*)d_ws;
  float*    qf       = (float*)   (ws);                  // 33,554,432
  bf16*     lklv     = (bf16*)    (ws + 33554432);       // 33,554,432
  _Float16* qh       = (_Float16*)(ws + 67108864);       // region A
  bf16*     VT       = (bf16*)    (ws + 67108864);       // region A overlay
  bf16*     hbf      = (bf16*)    (ws + 83886080);       // region B
  _Float16* hidh     = (_Float16*)(ws + 83886080);       // region B overlay
  bf16*     merged   = (bf16*)    (ws + 83886080);       // region B overlay
  bf16*     bt_lklv  = (bf16*)    (ws + 100663296);      // region C
  _Float16* hidl     = (_Float16*)(ws + 100663296);      // region C overlay
  bf16*     sp       = (bf16*)    (ws + 100663296);      // region C overlay
  float*    WkvTs    = (float*)   (ws + 117440512);      //  2,097,152 (x1024)
  bf16*     WoT      = (bf16*)    (ws + 119537664);      //  8,388,608
  float*    entriesF = (float*)   (ws + 127926272);      //  8,388,608
  float*    ckvF     = (float*)   (ws + 136314880);      //  1,048,576
  _Float16* ckh      = (_Float16*)(ws + 137363456);      //    262,144
  _Float16* ckl      = (_Float16*)(ws + 137625600);      //    262,144
  float*    wlog     = (float*)   (ws + 137887744);      //     16,384
  float*    wsm      = (float*)   (ws + 137904128);      //     16,384
  float*    bQ       = (float*)   (ws + 137920512);      //      8,192
  float*    bLKLV    = (float*)   (ws + 137928704);      //     16,384
  float*    bKV      = (float*)   (ws + 137945088);      //      1,024
  float*    bO       = (float*)   (ws + 137946112);      //      8,192
  _Float16* wqh      = (_Float16*)(ws + 137954304);      // region D (8,388,608)
  _Float16* wql      = (_Float16*)(ws + 146342912);      // region D (8,388,608)
  _Float16* ql       = (_Float16*)(ws + 137954304);      // region D overlay (16.7M)

  cvt_bias_k<<<dim3(8192), dim3(256), 0, stream>>>(hidden, hbf, bq, blk, blv, bk, bv, bo,
                                                   bQ, bLKLV, bKV, bO);
  transpose3_k<<<dim3(32, 32, 3), dim3(256), 0, stream>>>(Wlk, Wlv, Wo, bt_lklv, WoT);
  trans_f32s_kv<<<dim3(2, 32, 2), dim3(256), 0, stream>>>(Wk, Wv, WkvTs);

  wlog_k<<<dim3(1024), dim3(256), 0, stream>>>(hidden, Wcmp, bcmp, wlog);
  wsm_k<<<dim3(4), dim3(256), 0, stream>>>(wlog, wsm);
  entries_k<<<dim3(8192), dim3(256), 0, stream>>>(hidden, wsm, entriesF);

  // lk|lv projection first (consumes hbf + bt_lklv, freeing both regions)
  gemm_bt<bf16><<<dim3(32, 32), dim3(256), 0, stream>>>(hbf, bt_lklv, bLKLV, lklv, S_LEN, 4096, HID_, HID_);
  // small precise ckv projection (in-kernel split ok at this size)
  gemm_prec4<<<dim3(2, 8), dim3(256), 0, stream>>>(entriesF, WkvTs, bKV, ckvF, C_, 256, HID_, HID_);

  // precise q projection: pre-split operands, global_load_lds staging
  split_q_k<<<dim3(8192), dim3(256), 0, stream>>>(hidden, hidh, hidl);
  trans_split_wq<<<dim3(32, 32), dim3(256), 0, stream>>>(Wq, wqh, wql);
  gemm_hl4<<<dim3(16, 32), dim3(256), 0, stream>>>(hidh, hidl, wqh, wql, bQ, qf, S_LEN, HID_, HID_, HID_);

  // norms + rope (q: trig shared across heads, fp16 split fused; qh/ql overlay dead regions)
  normrope64_q<<<dim3(4096), dim3(256), 0, stream>>>(qf, qn_w, qh, ql);
  normrope64_ck<<<dim3(256), dim3(256), 0, stream>>>(ckvF, kn_w, ckh, ckl);
  normrope_bf_l<<<dim3(4096), dim3(256), 0, stream>>>(lklv, kn_w);

  // attention branches
  sparse_v10<<<dim3(512, 8), dim3(1024), 0, stream>>>(qh, ql, ckh, ckl, ckvF, sp);
  trans_v_k<<<dim3(64, 32), dim3(256), 0, stream>>>(lklv, VT);
  local_mfma<<<dim3(128, 16), dim3(128), 0, stream>>>(qf, lklv, VT, sp, merged);

  // output projection
  gemm_bt<float><<<dim3(16, 32), dim3(256), 0, stream>>>(merged, WoT, bO, out, S_LEN, HID_, HID_, HID_);
}

// Round 7
// 1040.463 us; speedup vs baseline: 1.1725x; 1.1725x over previous
//
#include <hip/hip_runtime.h>
#include <hip/hip_bf16.h>
#include <hip/hip_fp16.h>
#include <stdint.h>

typedef __hip_bfloat16 bf16;
using bf16x8 = __attribute__((ext_vector_type(8))) short;     // 8 bf16
using half8  = __attribute__((ext_vector_type(8))) _Float16;  // 8 fp16
using f32x4  = __attribute__((ext_vector_type(4))) float;

#define S_LEN   4096
#define HID_    2048
#define NH_     16
#define D_      128
#define C_      1024
#define SCALE_  0.08838834764831845f   // 1/sqrt(128)
#define DESC_   (1.0 / 1048576.0)      // 2^-20 (undo ×1024 on both operands)

__device__ __forceinline__ void storeC(float* p, float v) { *p = v; }
__device__ __forceinline__ void storeC(bf16* p, float v)  { *p = __float2bfloat16(v); }
__device__ __forceinline__ void split2(float x, _Float16& h, _Float16& l) {
  h = (_Float16)x; l = (_Float16)(x - (float)h);
}
__device__ __forceinline__ short bf2s(bf16 b) { short s; __builtin_memcpy(&s, &b, 2); return s; }

#define GLDS(src, dst) __builtin_amdgcn_global_load_lds( \
    (const __attribute__((address_space(1))) void*)(src), \
    (__attribute__((address_space(3))) void*)(dst), 16, 0, 0)

// ---------------- fp32 -> bf16 convert (hidden) + bias concat (fused) ----------------
__global__ __launch_bounds__(256) void cvt_bias_k(const float* __restrict__ src, bf16* __restrict__ dst,
                                                  const float* bq, const float* blk, const float* blv,
                                                  const float* bk, const float* bv, const float* bo,
                                                  float* bQ, float* bLKLV, float* bKV, float* bO) {
  int i = (blockIdx.x * 256 + threadIdx.x) * 4;
  float4 v = *(const float4*)(src + i);
  bf16 o[4] = {__float2bfloat16(v.x), __float2bfloat16(v.y),
               __float2bfloat16(v.z), __float2bfloat16(v.w)};
  *(uint2*)(dst + i) = *(uint2*)o;
  int ib = blockIdx.x * 256 + threadIdx.x;
  if (ib < 8448) {
    if (ib < 2048)      bQ[ib] = bq[ib];
    else if (ib < 6144) { int j = ib - 2048; bLKLV[j] = (j < 2048) ? blk[j] : blv[j - 2048]; }
    else if (ib < 6400) { int j = ib - 6144; bKV[j] = (j < 128) ? bk[j] : bv[j - 128]; }
    else                bO[ib - 6400] = bo[ib - 6400];
  }
}

// ---------------- fp32 -> fp16 hi/lo split (x1024), contiguous (hidden pre-split) ----------------
__global__ __launch_bounds__(256) void split_q_k(const float* __restrict__ src,
                                                 _Float16* __restrict__ oh, _Float16* __restrict__ ol) {
  int i = (blockIdx.x * 256 + threadIdx.x) * 4;
  float4 v = *(const float4*)(src + i);
  float xs[4] = {v.x, v.y, v.z, v.w};
  _Float16 hh[4], ll[4];
#pragma unroll
  for (int e = 0; e < 4; ++e) split2(xs[e] * 1024.0f, hh[e], ll[e]);
  *(uint2*)(oh + i) = *(uint2*)hh;
  *(uint2*)(ol + i) = *(uint2*)ll;
}

// ---------------- Wq transpose + x1024 + hi/lo split (fused) ----------------
__global__ __launch_bounds__(256) void trans_split_wq(const float* __restrict__ src,
                                                      _Float16* __restrict__ oh, _Float16* __restrict__ ol) {
  __shared__ float tile[64][65];
  const int c0 = blockIdx.x * 64, r0 = blockIdx.y * 64;
  const int t = threadIdx.x, cc = t & 63, rb = t >> 6;
#pragma unroll
  for (int i = 0; i < 16; ++i) {
    int r = rb + i * 4;
    tile[r][cc] = src[(size_t)(r0 + r) * HID_ + c0 + cc];
  }
  __syncthreads();
#pragma unroll
  for (int i = 0; i < 16; ++i) {
    int r = rb + i * 4;
    float x = tile[cc][r] * 1024.0f;           // same value gemm_prec4's B-path saw
    _Float16 h, l; split2(x, h, l);
    size_t off = (size_t)(c0 + r) * HID_ + r0 + cc;
    oh[off] = h; ol[off] = l;
  }
}

// ---------------- 3-way transpose: fp32 (2048x2048) -> bf16 (2048x2048), z selects matrix ----------------
__global__ __launch_bounds__(256) void transpose3_k(const float* __restrict__ Wlk, const float* __restrict__ Wlv,
                                                    const float* __restrict__ Wo,
                                                    bf16* __restrict__ bt_lklv, bf16* __restrict__ WoT) {
  __shared__ float tile[64][65];
  const float* src = (blockIdx.z == 0) ? Wlk : (blockIdx.z == 1) ? Wlv : Wo;
  bf16* dst = (blockIdx.z == 0) ? bt_lklv
            : (blockIdx.z == 1) ? (bt_lklv + (size_t)2048 * HID_) : WoT;
  const int c0 = blockIdx.x * 64, r0 = blockIdx.y * 64;
  const int t = threadIdx.x, cc = t & 63, rb = t >> 6;
#pragma unroll
  for (int i = 0; i < 16; ++i) {
    int r = rb + i * 4;
    tile[r][cc] = src[(size_t)(r0 + r) * HID_ + c0 + cc];
  }
  __syncthreads();
#pragma unroll
  for (int i = 0; i < 16; ++i) {
    int r = rb + i * 4;
    dst[(size_t)(c0 + r) * HID_ + r0 + cc] = __float2bfloat16(tile[cc][r]);
  }
}

// ---------------- Wk/Wv transpose + x1024 (z selects) ----------------
__global__ __launch_bounds__(256) void trans_f32s_kv(const float* __restrict__ Wk, const float* __restrict__ Wv,
                                                     float* __restrict__ WkvTs) {
  __shared__ float tile[64][65];
  const float* src = blockIdx.z ? Wv : Wk;
  float* dst = WkvTs + (blockIdx.z ? (size_t)128 * HID_ : 0);
  const int c0 = blockIdx.x * 64, r0 = blockIdx.y * 64;
  const int t = threadIdx.x, cc = t & 63, rb = t >> 6;
#pragma unroll
  for (int i = 0; i < 16; ++i) {
    int r = rb + i * 4;
    tile[r][cc] = src[(size_t)(r0 + r) * 128 + c0 + cc];
  }
  __syncthreads();
#pragma unroll
  for (int i = 0; i < 16; ++i) {
    int r = rb + i * 4;
    dst[(size_t)(c0 + r) * HID_ + r0 + cc] = tile[cc][r] * 1024.0f;
  }
}

// ---------------- transpose lv half of lklv (bf16 [4096][2048-slice]) -> VT [2048][4096] ----------------
__global__ __launch_bounds__(256) void trans_v_k(const bf16* __restrict__ lklv, bf16* __restrict__ VT) {
  __shared__ ushort tile[64][65];
  const int s0 = blockIdx.x * 64, c0 = blockIdx.y * 64;
  const int t = threadIdx.x, cc = t & 63, rb = t >> 6;
  const ushort* src = (const ushort*)lklv;
#pragma unroll
  for (int i = 0; i < 16; ++i) {
    int r = rb + i * 4;
    tile[r][cc] = src[(size_t)(s0 + r) * 4096 + 2048 + c0 + cc];
  }
  __syncthreads();
  ushort* dst = (ushort*)VT;
#pragma unroll
  for (int i = 0; i < 16; ++i) {
    int r = rb + i * 4;
    dst[(size_t)(c0 + r) * 4096 + s0 + cc] = tile[cc][r];
  }
}

// ---------------- plain m97-style bf16 GEMM ----------------
template <typename OutT>
__global__ __launch_bounds__(256) void gemm_bt(const bf16* __restrict__ A, const bf16* __restrict__ BT,
                                               const float* __restrict__ bias, OutT* __restrict__ Cmat,
                                               int M, int N, int K, int lda) {
  __shared__ bf16 As[128 * 32];
  __shared__ bf16 Bs[128 * 32];
  const int t = threadIdx.x;
  const int wave = t >> 6, lane = t & 63;
  const int wr = wave >> 1, wc = wave & 1;
  const int quad = lane >> 4, l15 = lane & 15;
  const int bx = blockIdx.x * 128, by = blockIdx.y * 128;
  const int srow = t >> 2, scol = (t & 3) * 8;
  f32x4 acc[4][4] = {};
  const bf16* a0 = A + (size_t)(by + srow) * lda + scol;
  const bf16* a1 = A + (size_t)(by + 64 + srow) * lda + scol;
  const bf16* b0 = BT + (size_t)(bx + srow) * K + scol;
  const bf16* b1 = BT + (size_t)(bx + 64 + srow) * K + scol;
  for (int k0 = 0; k0 < K; k0 += 32) {
    GLDS(a0 + k0, As + t * 8);
    GLDS(a1 + k0, As + 2048 + t * 8);
    GLDS(b0 + k0, Bs + t * 8);
    GLDS(b1 + k0, Bs + 2048 + t * 8);
    __syncthreads();
    bf16x8 aF[4], bF[4];
#pragma unroll
    for (int i = 0; i < 4; ++i)
      aF[i] = *(const bf16x8*)(As + (wr * 64 + i * 16 + l15) * 32 + quad * 8);
#pragma unroll
    for (int j = 0; j < 4; ++j)
      bF[j] = *(const bf16x8*)(Bs + (wc * 64 + j * 16 + l15) * 32 + quad * 8);
#pragma unroll
    for (int i = 0; i < 4; ++i)
#pragma unroll
      for (int j = 0; j < 4; ++j)
        acc[i][j] = __builtin_amdgcn_mfma_f32_16x16x32_bf16(aF[i], bF[j], acc[i][j], 0, 0, 0);
    __syncthreads();
  }
#pragma unroll
  for (int i = 0; i < 4; ++i)
#pragma unroll
    for (int j = 0; j < 4; ++j)
#pragma unroll
      for (int r = 0; r < 4; ++r) {
        int row = by + wr * 64 + i * 16 + quad * 4 + r;
        int col = bx + wc * 64 + j * 16 + l15;
        storeC(&Cmat[(size_t)row * N + col], acc[i][j][r] + bias[col]);
      }
}

// ---------------- precise GEMM, pre-split operands + global_load_lds staging ----------------
__global__ __launch_bounds__(256) void gemm_hl4(const _Float16* __restrict__ Ah, const _Float16* __restrict__ Al,
                                                const _Float16* __restrict__ Bh, const _Float16* __restrict__ Bl,
                                                const float* __restrict__ bias, float* __restrict__ Cmat,
                                                int M, int N, int K, int lda) {
  __shared__ _Float16 Ahs[128 * 32], Als[128 * 32], Bhs[128 * 32], Bls[128 * 32];
  const int t = threadIdx.x;
  const int wave = t >> 6, lane = t & 63;
  const int wr = wave >> 1, wc = wave & 1;
  const int quad = lane >> 4, l15 = lane & 15;
  const int bx = blockIdx.x * 128, by = blockIdx.y * 128;
  const int srow = t >> 2, scol = (t & 3) * 8;
  double acc[4][4][4] = {};
  const _Float16* a0h = Ah + (size_t)(by + srow) * lda + scol;
  const _Float16* a1h = Ah + (size_t)(by + 64 + srow) * lda + scol;
  const _Float16* a0l = Al + (size_t)(by + srow) * lda + scol;
  const _Float16* a1l = Al + (size_t)(by + 64 + srow) * lda + scol;
  const _Float16* b0h = Bh + (size_t)(bx + srow) * K + scol;
  const _Float16* b1h = Bh + (size_t)(bx + 64 + srow) * K + scol;
  const _Float16* b0l = Bl + (size_t)(bx + srow) * K + scol;
  const _Float16* b1l = Bl + (size_t)(bx + 64 + srow) * K + scol;
  for (int k0 = 0; k0 < K; k0 += 32) {
    GLDS(a0h + k0, Ahs + t * 8);
    GLDS(a1h + k0, Ahs + 2048 + t * 8);
    GLDS(a0l + k0, Als + t * 8);
    GLDS(a1l + k0, Als + 2048 + t * 8);
    GLDS(b0h + k0, Bhs + t * 8);
    GLDS(b1h + k0, Bhs + 2048 + t * 8);
    GLDS(b0l + k0, Bls + t * 8);
    GLDS(b1l + k0, Bls + 2048 + t * 8);
    __syncthreads();
    half8 aFh[4], aFl[4], bFh[4], bFl[4];
#pragma unroll
    for (int i = 0; i < 4; ++i) {
      int ro = (wr * 64 + i * 16 + l15) * 32 + quad * 8;
      aFh[i] = *(const half8*)(Ahs + ro);
      aFl[i] = *(const half8*)(Als + ro);
    }
#pragma unroll
    for (int j = 0; j < 4; ++j) {
      int ro = (wc * 64 + j * 16 + l15) * 32 + quad * 8;
      bFh[j] = *(const half8*)(Bhs + ro);
      bFl[j] = *(const half8*)(Bls + ro);
    }
#pragma unroll
    for (int i = 0; i < 4; ++i)
#pragma unroll
      for (int j = 0; j < 4; ++j) {
        f32x4 tt = {0.f, 0.f, 0.f, 0.f};
        tt = __builtin_amdgcn_mfma_f32_16x16x32_f16(aFl[i], bFl[j], tt, 0, 0, 0);
        tt = __builtin_amdgcn_mfma_f32_16x16x32_f16(aFl[i], bFh[j], tt, 0, 0, 0);
        tt = __builtin_amdgcn_mfma_f32_16x16x32_f16(aFh[i], bFl[j], tt, 0, 0, 0);
        tt = __builtin_amdgcn_mfma_f32_16x16x32_f16(aFh[i], bFh[j], tt, 0, 0, 0);
#pragma unroll
        for (int r = 0; r < 4; ++r) acc[i][j][r] += (double)tt[r];
      }
    __syncthreads();
  }
#pragma unroll
  for (int i = 0; i < 4; ++i)
#pragma unroll
    for (int j = 0; j < 4; ++j)
#pragma unroll
      for (int r = 0; r < 4; ++r) {
        int row = by + wr * 64 + i * 16 + quad * 4 + r;
        int col = bx + wc * 64 + j * 16 + l15;
        Cmat[(size_t)row * N + col] = (float)(acc[i][j][r] * DESC_ + (double)bias[col]);
      }
}

// ---------------- precise GEMM with in-kernel split (kept for small ckv projection) ----------------
__global__ __launch_bounds__(256) void gemm_prec4(const float* __restrict__ A, const float* __restrict__ BT,
                                                  const float* __restrict__ bias, float* __restrict__ Cmat,
                                                  int M, int N, int K, int lda) {
  __shared__ _Float16 Ah[128 * 32], Al[128 * 32], Bh[128 * 32], Bl[128 * 32];
  const int t = threadIdx.x;
  const int wave = t >> 6, lane = t & 63;
  const int wr = wave >> 1, wc = wave & 1;
  const int quad = lane >> 4, l15 = lane & 15;
  const int bx = blockIdx.x * 128, by = blockIdx.y * 128;
  double acc[4][4][4] = {};
  for (int k0 = 0; k0 < K; k0 += 32) {
#pragma unroll
    for (int it = 0; it < 4; ++it) {
      int sl = t + it * 256;
      int isB = sl >> 9, s2 = sl & 511, r = s2 >> 2, g = s2 & 3;
      const float* src = isB ? (BT + (size_t)(bx + r) * K + k0 + g * 8)
                             : (A  + (size_t)(by + r) * lda + k0 + g * 8);
      float4 u = ((const float4*)src)[0];
      float4 v = ((const float4*)src)[1];
      float xs[8] = {u.x, u.y, u.z, u.w, v.x, v.y, v.z, v.w};
      half8 hh, ll;
#pragma unroll
      for (int e = 0; e < 8; ++e) {
        float x = isB ? xs[e] : xs[e] * 1024.0f;
        _Float16 h, l; split2(x, h, l);
        hh[e] = h; ll[e] = l;
      }
      _Float16* dh = (isB ? Bh : Ah) + r * 32 + g * 8;
      _Float16* dl = (isB ? Bl : Al) + r * 32 + g * 8;
      *(half8*)dh = hh;
      *(half8*)dl = ll;
    }
    __syncthreads();
    half8 aFh[4], aFl[4], bFh[4], bFl[4];
#pragma unroll
    for (int i = 0; i < 4; ++i) {
      int ro = (wr * 64 + i * 16 + l15) * 32 + quad * 8;
      aFh[i] = *(const half8*)(Ah + ro);
      aFl[i] = *(const half8*)(Al + ro);
    }
#pragma unroll
    for (int j = 0; j < 4; ++j) {
      int ro = (wc * 64 + j * 16 + l15) * 32 + quad * 8;
      bFh[j] = *(const half8*)(Bh + ro);
      bFl[j] = *(const half8*)(Bl + ro);
    }
#pragma unroll
    for (int i = 0; i < 4; ++i)
#pragma unroll
      for (int j = 0; j < 4; ++j) {
        f32x4 tt = {0.f, 0.f, 0.f, 0.f};
        tt = __builtin_amdgcn_mfma_f32_16x16x32_f16(aFl[i], bFl[j], tt, 0, 0, 0);
        tt = __builtin_amdgcn_mfma_f32_16x16x32_f16(aFl[i], bFh[j], tt, 0, 0, 0);
        tt = __builtin_amdgcn_mfma_f32_16x16x32_f16(aFh[i], bFl[j], tt, 0, 0, 0);
        tt = __builtin_amdgcn_mfma_f32_16x16x32_f16(aFh[i], bFh[j], tt, 0, 0, 0);
#pragma unroll
        for (int r = 0; r < 4; ++r) acc[i][j][r] += (double)tt[r];
      }
    __syncthreads();
  }
#pragma unroll
  for (int i = 0; i < 4; ++i)
#pragma unroll
    for (int j = 0; j < 4; ++j)
#pragma unroll
      for (int r = 0; r < 4; ++r) {
        int row = by + wr * 64 + i * 16 + quad * 4 + r;
        int col = bx + wc * 64 + j * 16 + l15;
        Cmat[(size_t)row * N + col] = (float)(acc[i][j][r] * DESC_ + (double)bias[col]);
      }
}

// ---------------- fp64 rmsnorm + rope for q: one block per s, trig shared across 16 heads ----------------
__global__ __launch_bounds__(256) void normrope64_q(float* __restrict__ base, const float* __restrict__ w,
                                                    _Float16* __restrict__ qh, _Float16* __restrict__ ql) {
  __shared__ double csd[32], snd[32];
  const int s = blockIdx.x;
  const int t = threadIdx.x, wv = t >> 6, lane = t & 63;
  if (t < 32) {
    float invf = 1.0f / (float)pow(10000.0, (double)t * (1.0 / 32.0));
    float angf = (float)s * invf;
    double ang = (double)angf;
    csd[t] = cos(ang);
    snd[t] = sin(ang);
  }
  __syncthreads();
  const int fi = lane & 31;
  float* ps = base + (size_t)s * HID_;
  for (int h = wv; h < 16; h += 4) {
    float* p = ps + h * 128;
    double x0 = (double)p[lane];
    double x1 = (double)p[lane + 64];
    double ss = x0 * x0 + x1 * x1;
#pragma unroll
    for (int m = 32; m; m >>= 1) ss += __shfl_xor(ss, m, 64);
    double rstd = 1.0 / sqrt(ss * (1.0 / 128.0) + 1e-6);
    double n0 = x0 * rstd * (double)w[lane];
    double n1 = x1 * rstd * (double)w[lane + 64];
    double other = __shfl_xor(n0, 32, 64);
    double cs = csd[fi], sn = snd[fi];
    double r0 = (lane < 32) ? (n0 * cs - other * sn) : (other * sn + n0 * cs);
    float f0 = (float)r0, f1 = (float)n1;
    p[lane] = f0;
    p[lane + 64] = f1;
    _Float16 h0, l0, h1, l1;
    split2(f0 * 1024.0f, h0, l0);
    split2(f1 * 1024.0f, h1, l1);
    size_t off = (size_t)s * HID_ + h * 128;
    qh[off + lane] = h0;       ql[off + lane] = l0;
    qh[off + 64 + lane] = h1;  ql[off + 64 + lane] = l1;
  }
}

// ---------------- fp64 rmsnorm + rope for ckv rows + fused fp16 hi/lo split ----------------
__global__ __launch_bounds__(256) void normrope64_ck(float* __restrict__ base, const float* __restrict__ w,
                                                     _Float16* __restrict__ ckh, _Float16* __restrict__ ckl) {
  int row = blockIdx.x * 4 + (threadIdx.x >> 6);   // grid 256 -> rows 0..1023
  int lane = threadIdx.x & 63;
  float* p = base + (size_t)row * 256;
  double x0 = (double)p[lane];
  double x1 = (double)p[lane + 64];
  double ss = x0 * x0 + x1 * x1;
#pragma unroll
  for (int m = 32; m; m >>= 1) ss += __shfl_xor(ss, m, 64);
  double rstd = 1.0 / sqrt(ss * (1.0 / 128.0) + 1e-6);
  double n0 = x0 * rstd * (double)w[lane];
  double n1 = x1 * rstd * (double)w[lane + 64];
  double other = __shfl_xor(n0, 32, 64);
  int fi = lane & 31;
  float invf = 1.0f / (float)pow(10000.0, (double)fi * (1.0 / 32.0));
  float angf = (float)(row * 4 + 3) * invf;
  double ang = (double)angf;
  double cs = cos(ang), sn = sin(ang);
  double r0 = (lane < 32) ? (n0 * cs - other * sn) : (other * sn + n0 * cs);
  float f0 = (float)r0, f1 = (float)n1;
  p[lane] = f0;
  p[lane + 64] = f1;
  _Float16 h0, l0, h1, l1;                          // identical to old split_ck_k on stored values
  split2(f0 * 1024.0f, h0, l0);
  split2(f1 * 1024.0f, h1, l1);
  ckh[row * 128 + lane] = h0;       ckl[row * 128 + lane] = l0;
  ckh[row * 128 + 64 + lane] = h1;  ckl[row * 128 + 64 + lane] = l1;
}

// ---------------- bf16 rmsnorm+rope for lk: one block per s, trig shared across 16 heads ----------------
__global__ __launch_bounds__(256) void normrope_bf_l(bf16* __restrict__ base, const float* __restrict__ w) {
  __shared__ float csf[32], snf[32];
  const int s = blockIdx.x;
  const int t = threadIdx.x, wv = t >> 6, lane = t & 63;
  if (t < 32) {
    float invf = 1.0f / (float)pow(10000.0, (double)t * (1.0 / 32.0));
    float ang = (float)s * invf;
    csf[t] = cosf(ang);
    snf[t] = sinf(ang);
  }
  __syncthreads();
  const int fi = lane & 31;
  bf16* ps = base + (size_t)s * 4096;
  for (int h = wv; h < 16; h += 4) {
    bf16* p = ps + h * 128;
    float x0 = __bfloat162float(p[lane]);
    float x1 = __bfloat162float(p[lane + 64]);
    float ss = x0 * x0 + x1 * x1;
#pragma unroll
    for (int m = 32; m; m >>= 1) ss += __shfl_xor(ss, m, 64);
    float rstd = rsqrtf(ss * 0.0078125f + 1e-6f);
    float n0 = x0 * rstd * w[lane];
    float n1 = x1 * rstd * w[lane + 64];
    float other = __shfl_xor(n0, 32, 64);
    float cs = csf[fi], sn = snf[fi];
    float r0 = (lane < 32) ? (n0 * cs - other * sn) : (other * sn + n0 * cs);
    p[lane] = __float2bfloat16(r0);
    p[lane + 64] = __float2bfloat16(n1);
  }
}

// ---------------- compress logits (fp64) ----------------
__global__ __launch_bounds__(256) void wlog_k(const float* __restrict__ hidden, const float* __restrict__ wcmp,
                                              const float* __restrict__ bcmp, float* __restrict__ wlog) {
  int s = blockIdx.x * 4 + (threadIdx.x >> 6);
  int lane = threadIdx.x & 63;
  const float* hp = hidden + (size_t)s * HID_;
  double acc = 0.0;
  for (int i = lane; i < HID_; i += 64)
    acc += (double)hp[i] * (double)wcmp[i];
#pragma unroll
  for (int m = 32; m; m >>= 1) acc += __shfl_xor(acc, m, 64);
  if (lane == 0) wlog[s] = (float)(acc + (double)bcmp[0]);
}

__global__ void wsm_k(const float* __restrict__ wlog, float* __restrict__ wsm) {
  int c = blockIdx.x * 256 + threadIdx.x;
  if (c >= C_) return;
  double v[4], m = -1e300;
#pragma unroll
  for (int r = 0; r < 4; ++r) { v[r] = (double)wlog[4 * c + r]; if (v[r] > m) m = v[r]; }
  double sum = 0.0;
#pragma unroll
  for (int r = 0; r < 4; ++r) { v[r] = exp(v[r] - m); sum += v[r]; }
#pragma unroll
  for (int r = 0; r < 4; ++r) wsm[4 * c + r] = (float)(v[r] / sum);
}

__global__ __launch_bounds__(256) void entries_k(const float* __restrict__ hidden, const float* __restrict__ wsm,
                                                 float* __restrict__ entriesF) {
  int idx = blockIdx.x * 256 + threadIdx.x;     // c*2048 + hcol
  int c = idx >> 11, hcol = idx & 2047;
  double e = 0.0;
#pragma unroll
  for (int r = 0; r < 4; ++r)
    e += (double)wsm[4 * c + r] * (double)hidden[(size_t)(4 * c + r) * HID_ + hcol];
  entriesF[idx] = (float)e;
}

// ---------------- sparse v9 (verbatim from the R5 passing build) ----------------
__global__ __launch_bounds__(1024, 8) void sparse_v9(const _Float16* __restrict__ qh, const _Float16* __restrict__ ql,
                                                     const _Float16* __restrict__ ckh, const _Float16* __restrict__ ckl,
                                                     const float* __restrict__ ckvF, bf16* __restrict__ sp) {
  __shared__ float sc[16 * 1024];               // 64 KB -> 2 blocks/CU
  const int by = blockIdx.y;                    // head pair: heads 2*by, 2*by+1
  const int s0 = blockIdx.x * 8;
  const int t = threadIdx.x, w = t >> 6, lane = t & 63;
  const int quad = lane >> 4, l15 = lane & 15;
  const int nvmax  = (s0 >> 2) + 2;             // max causally valid blocks for s in [s0,s0+8)
  const int ntiles = (nvmax + 15) >> 4;
  const double esc = (double)SCALE_ * DESC_;

  // ---- phase 1: score tiles distributed over 16 waves (A rows = 16 (q,h) chains) ----
  if (w < ntiles) {
    const int sA = s0 + (l15 & 7);
    const int hA = 2 * by + (l15 >> 3);
    half8 aFh[4], aFl[4];
    {
      const _Float16* qbh = qh + (size_t)sA * HID_ + hA * 128 + quad * 8;
      const _Float16* qbl = ql + (size_t)sA * HID_ + hA * 128 + quad * 8;
#pragma unroll
      for (int kk = 0; kk < 4; ++kk) {
        aFh[kk] = *(const half8*)(qbh + kk * 32);
        aFl[kk] = *(const half8*)(qbl + kk * 32);
      }
    }
    for (int ct = w; ct < ntiles; ct += 16) {
      const int c0 = ct * 16;
      const _Float16* kbh = ckh + (size_t)(c0 + l15) * 128 + quad * 8;
      const _Float16* kbl = ckl + (size_t)(c0 + l15) * 128 + quad * 8;
      double a64[4] = {0.0, 0.0, 0.0, 0.0};
#pragma unroll
      for (int kk = 0; kk < 4; ++kk) {
        half8 bh = *(const half8*)(kbh + kk * 32);
        half8 bl = *(const half8*)(kbl + kk * 32);
        f32x4 tt = {0.f, 0.f, 0.f, 0.f};
        tt = __builtin_amdgcn_mfma_f32_16x16x32_f16(aFl[kk], bl, tt, 0, 0, 0);
        tt = __builtin_amdgcn_mfma_f32_16x16x32_f16(aFl[kk], bh, tt, 0, 0, 0);
        tt = __builtin_amdgcn_mfma_f32_16x16x32_f16(aFh[kk], bl, tt, 0, 0, 0);
        tt = __builtin_amdgcn_mfma_f32_16x16x32_f16(aFh[kk], bh, tt, 0, 0, 0);
#pragma unroll
        for (int r = 0; r < 4; ++r) a64[r] += (double)tt[r];
      }
#pragma unroll
      for (int r = 0; r < 4; ++r)
        sc[(quad * 4 + r) * 1024 + c0 + l15] = (float)(a64[r] * esc);
    }
  }
  __syncthreads();
  if (w >= 4) return;

  // ---- phase 2: chain q = w*4 + quad, handled by 16 lanes (l15) ----
  const int q = w * 4 + quad;                   // == row in sc
  const int p2 = q >> 3, wq = q & 7;
  const int s = s0 + wq;
  const int nv = (s >= 3) ? (((s - 3) >> 2) + 1) : 0;
  const float* srow = sc + q * 1024;
  const int jmaxB = (nvmax + 63) >> 6;          // block-uniform j-tile count (1..16)

  // per-lane top-4 cache (tv[0] best; stable: ascending c, strict >)
  float tv0 = -1e38f, tv1 = -1e38f, tv2 = -1e38f, tv3 = -1e38f;
  int   ti0 = 0x40000000, ti1 = 0x40000000, ti2 = 0x40000000, ti3 = 0x40000000;
  for (int j = 0; j < jmaxB; ++j) {
    int cb = j * 64 + l15 * 4;
    float4 vv = *(const float4*)(srow + cb);
    float xs[4] = {vv.x, vv.y, vv.z, vv.w};
#pragma unroll
    for (int e = 0; e < 4; ++e) {
      int c = cb + e;
      float v = (c < nv) ? xs[e] : -1e38f;
      if (v > tv3) {
        if (v > tv0)      { tv3=tv2;ti3=ti2; tv2=tv1;ti2=ti1; tv1=tv0;ti1=ti0; tv0=v;ti0=c; }
        else if (v > tv1) { tv3=tv2;ti3=ti2; tv2=tv1;ti2=ti1; tv1=v;ti1=c; }
        else if (v > tv2) { tv3=tv2;ti3=ti2; tv2=v;ti2=c; }
        else              { tv3=v;ti3=c; }
      }
    }
  }

  unsigned long long deadm = 0ull;
  int ncons = 0;
  float bvs[8]; int bis[8];
#pragma unroll
  for (int it = 0; it < 8; ++it) {
    float bv = tv0; int bi = ti0;
#pragma unroll
    for (int mm = 1; mm <= 8; mm <<= 1) {
      float ov = __shfl_xor(bv, mm, 64);
      int   oi = __shfl_xor(bi, mm, 64);
      if (ov > bv || (ov == bv && oi < bi)) { bv = ov; bi = oi; }
    }
    bvs[it] = bv; bis[it] = bi;
    if (bv > -1e29f && (((bi >> 2) & 15) == l15)) {  // this lane owned the winner
      deadm |= 1ull << (((bi >> 6) << 2) | (bi & 3));
      tv0=tv1;ti0=ti1; tv1=tv2;ti1=ti2; tv2=tv3;ti2=ti3;
      tv3=-1e38f; ti3=0x40000000;
      if (++ncons == 4) {                            // cache exhausted: rebuild (rare)
        ncons = 0;
        tv0=tv1=tv2=tv3=-1e38f;
        ti0=ti1=ti2=ti3=0x40000000;
        for (int j = 0; j < jmaxB; ++j) {
          int cb = j * 64 + l15 * 4;
          float4 vv = *(const float4*)(srow + cb);
          float xs[4] = {vv.x, vv.y, vv.z, vv.w};
#pragma unroll
          for (int e = 0; e < 4; ++e) {
            int c = cb + e;
            int li = ((c >> 6) << 2) | (c & 3);
            float v = (c < nv && !((deadm >> li) & 1ull)) ? xs[e] : -1e38f;
            if (v > tv3) {
              if (v > tv0)      { tv3=tv2;ti3=ti2; tv2=tv1;ti2=ti1; tv1=tv0;ti1=ti0; tv0=v;ti0=c; }
              else if (v > tv1) { tv3=tv2;ti3=ti2; tv2=tv1;ti2=ti1; tv1=v;ti1=c; }
              else if (v > tv2) { tv3=tv2;ti3=ti2; tv2=v;ti2=c; }
              else              { tv3=v;ti3=c; }
            }
          }
        }
      }
    }
  }

  // ---- gathers + softmax + output (16 lanes x 8 floats = 128 dims) ----
  const float m0 = bvs[0];
  float a0=0.f,a1=0.f,a2=0.f,a3=0.f,a4=0.f,a5=0.f,a6=0.f,a7=0.f;
  float esum = 0.f;
#pragma unroll
  for (int it = 0; it < 8; ++it) {
    if (bvs[it] > -1e29f) {
      float wgt = expf(bvs[it] - m0);
      esum += wgt;
      const float* cvp = ckvF + (size_t)bis[it] * 256 + 128 + l15 * 8;
      float4 u = *(const float4*)cvp;
      float4 v = *(const float4*)(cvp + 4);
      a0 += wgt*u.x; a1 += wgt*u.y; a2 += wgt*u.z; a3 += wgt*u.w;
      a4 += wgt*v.x; a5 += wgt*v.y; a6 += wgt*v.z; a7 += wgt*v.w;
    }
  }
  float inv = 1.0f / fmaxf(esum, 1e-9f);
  bf16* op = sp + (size_t)s * 2048 + (2 * by + p2) * 128 + l15 * 8;
  bf16 ob[8] = {__float2bfloat16(a0*inv), __float2bfloat16(a1*inv),
                __float2bfloat16(a2*inv), __float2bfloat16(a3*inv),
                __float2bfloat16(a4*inv), __float2bfloat16(a5*inv),
                __float2bfloat16(a6*inv), __float2bfloat16(a7*inv)};
  *(uint4*)op = *(uint4*)ob;
}

// ---------------- local sliding-window via MFMA ----------------
__global__ __launch_bounds__(128) void local_mfma(const float* __restrict__ qf,
                                                  const bf16* __restrict__ lklv,
                                                  const bf16* __restrict__ VT,
                                                  const bf16* __restrict__ sp,
                                                  bf16* __restrict__ merged) {
  constexpr int PADP = 168;
  __shared__ bf16 PhS[2][16 * PADP];
  __shared__ bf16 PlS[2][16 * PADP];
  const int h = blockIdx.y;
  const int t = threadIdx.x, w = t >> 6, lane = t & 63;
  const int quad = lane >> 4, l15 = lane & 15;
  const int sw = blockIdx.x * 32 + w * 16;
  const int kbase = sw - 128;
  const int ridx = quad * 4;

  bf16x8 qH[4], qL[4];
  {
    const float* qp = qf + (size_t)(sw + l15) * HID_ + h * 128 + quad * 8;
#pragma unroll
    for (int kk = 0; kk < 4; ++kk) {
      float4 u = *(const float4*)(qp + kk * 32);
      float4 v = *(const float4*)(qp + kk * 32 + 4);
      float xs[8] = {u.x, u.y, u.z, u.w, v.x, v.y, v.z, v.w};
      bf16x8 hh, ll;
#pragma unroll
      for (int e = 0; e < 8; ++e) {
        bf16 bh = __float2bfloat16(xs[e]);
        float fh = __bfloat162float(bh);
        bf16 bl = __float2bfloat16(xs[e] - fh);
        hh[e] = bf2s(bh); ll[e] = bf2s(bl);
      }
      qH[kk] = hh; qL[kk] = ll;
    }
  }

  float sc[9][4];
#pragma unroll
  for (int ct = 0; ct < 9; ++ct) {
    int key0 = kbase + ct * 16 + l15;
    const bf16* kp = lklv + (size_t)(key0 < 0 ? 0 : key0) * 4096 + h * 128 + quad * 8;
    f32x4 acc = {0.f, 0.f, 0.f, 0.f};
#pragma unroll
    for (int kk = 0; kk < 4; ++kk) {
      bf16x8 kb = *(const bf16x8*)(kp + kk * 32);
      acc = __builtin_amdgcn_mfma_f32_16x16x32_bf16(qL[kk], kb, acc, 0, 0, 0);
      acc = __builtin_amdgcn_mfma_f32_16x16x32_bf16(qH[kk], kb, acc, 0, 0, 0);
    }
#pragma unroll
    for (int r = 0; r < 4; ++r) sc[ct][r] = acc[r] * SCALE_;
  }

  float mrow[4] = {-1e30f, -1e30f, -1e30f, -1e30f};
#pragma unroll
  for (int ct = 0; ct < 9; ++ct) {
    int cidx = ct * 16 + l15;
#pragma unroll
    for (int r = 0; r < 4; ++r) {
      bool valid = (cidx >= ridx + r) && (cidx <= ridx + r + 128) && (kbase + cidx >= 0);
      float v = valid ? sc[ct][r] : -1e30f;
      sc[ct][r] = v;
      mrow[r] = fmaxf(mrow[r], v);
    }
  }
#pragma unroll
  for (int mm = 1; mm <= 8; mm <<= 1)
#pragma unroll
    for (int r = 0; r < 4; ++r) mrow[r] = fmaxf(mrow[r], __shfl_xor(mrow[r], mm, 64));

  bf16* phb = &PhS[w][0];
  bf16* plb = &PlS[w][0];
  for (int z = lane; z < 256; z += 64) {
    int zr = z >> 4, zc = z & 15;
    phb[zr * PADP + 144 + zc] = __float2bfloat16(0.f);
    plb[zr * PADP + 144 + zc] = __float2bfloat16(0.f);
  }
  float lsum[4] = {0.f, 0.f, 0.f, 0.f};
#pragma unroll
  for (int ct = 0; ct < 9; ++ct) {
    int cidx = ct * 16 + l15;
#pragma unroll
    for (int r = 0; r < 4; ++r) {
      float e = (sc[ct][r] > -1e29f) ? expf(sc[ct][r] - mrow[r]) : 0.f;
      lsum[r] += e;
      bf16 bh = __float2bfloat16(e);
      float fh = __bfloat162float(bh);
      bf16 bl = __float2bfloat16(e - fh);
      phb[(ridx + r) * PADP + cidx] = bh;
      plb[(ridx + r) * PADP + cidx] = bl;
    }
  }
#pragma unroll
  for (int mm = 1; mm <= 8; mm <<= 1)
#pragma unroll
    for (int r = 0; r < 4; ++r) lsum[r] += __shfl_xor(lsum[r], mm, 64);
  float inv[4];
#pragma unroll
  for (int r = 0; r < 4; ++r) inv[r] = 1.0f / lsum[r];

  bf16x8 pH[5], pL[5];
#pragma unroll
  for (int kk = 0; kk < 5; ++kk) {
    pH[kk] = *(const bf16x8*)(phb + l15 * PADP + kk * 32 + quad * 8);
    pL[kk] = *(const bf16x8*)(plb + l15 * PADP + kk * 32 + quad * 8);
  }

#pragma unroll
  for (int dt = 0; dt < 8; ++dt) {
    const bf16* vrow = VT + (size_t)(h * 128 + dt * 16 + l15) * 4096;
    f32x4 acc = {0.f, 0.f, 0.f, 0.f};
#pragma unroll
    for (int kk = 0; kk < 5; ++kk) {
      int ko = kbase + kk * 32 + quad * 8;
      ko = ko < 0 ? 0 : (ko > 4088 ? 4088 : ko);
      bf16x8 vb = *(const bf16x8*)(vrow + ko);
      acc = __builtin_amdgcn_mfma_f32_16x16x32_bf16(pL[kk], vb, acc, 0, 0, 0);
      acc = __builtin_amdgcn_mfma_f32_16x16x32_bf16(pH[kk], vb, acc, 0, 0, 0);
    }
#pragma unroll
    for (int r = 0; r < 4; ++r) {
      int srow = sw + ridx + r;
      size_t off = (size_t)srow * 2048 + h * 128 + dt * 16 + l15;
      float spv = __bfloat162float(sp[off]);
      merged[off] = __float2bfloat16((acc[r] * inv[r] + spv) * 0.5f);
    }
  }
}

// ---------------- host orchestration ----------------
extern "C" void kernel_launch(void* const* d_in, const int* in_sizes, int n_in,
                              void* d_out, int out_size, void* d_ws, size_t ws_size,
                              hipStream_t stream) {
  (void)in_sizes; (void)n_in; (void)out_size; (void)ws_size;
  const float* hidden = (const float*)d_in[0];
  const float* Wq   = (const float*)d_in[1];
  const float* bq   = (const float*)d_in[2];
  const float* Wcmp = (const float*)d_in[3];
  const float* bcmp = (const float*)d_in[4];
  const float* Wk   = (const float*)d_in[5];
  const float* bk   = (const float*)d_in[6];
  const float* Wv   = (const float*)d_in[7];
  const float* bv   = (const float*)d_in[8];
  const float* Wlk  = (const float*)d_in[9];
  const float* blk  = (const float*)d_in[10];
  const float* Wlv  = (const float*)d_in[11];
  const float* blv  = (const float*)d_in[12];
  const float* qn_w = (const float*)d_in[13];
  const float* kn_w = (const float*)d_in[14];
  const float* Wo   = (const float*)d_in[15];
  const float* bo   = (const float*)d_in[16];
  float* out = (float*)d_out;

  // workspace (~155 MB). Overlay timeline (all same-stream, serial):
  //  region A (67108864, 16.7M): qh (normrope_q..sparse) -> VT (trans_v..local)
  //  region B (83886080, 16.7M): hbf (cvt..lklv-gemm) -> hidh (split..gemm_hl4) -> merged (local..out-gemm)
  //  region C (100663296,16.7M): bt_lklv (transpose3..lklv-gemm) -> hidl (split..gemm_hl4) -> sp (sparse..local)
  //  region D (137954304,16.7M): wqh|wql (trans_split..gemm_hl4) -> ql (normrope_q..sparse)
  char* ws = (char*)d_ws;
  float*    qf       = (float*)   (ws);                  // 33,554,432
  bf16*     lklv     = (bf16*)    (ws + 33554432);       // 33,554,432
  _Float16* qh       = (_Float16*)(ws + 67108864);       // region A
  bf16*     VT       = (bf16*)    (ws + 67108864);       // region A overlay
  bf16*     hbf      = (bf16*)    (ws + 83886080);       // region B
  _Float16* hidh     = (_Float16*)(ws + 83886080);       // region B overlay
  bf16*     merged   = (bf16*)    (ws + 83886080);       // region B overlay
  bf16*     bt_lklv  = (bf16*)    (ws + 100663296);      // region C
  _Float16* hidl     = (_Float16*)(ws + 100663296);      // region C overlay
  bf16*     sp       = (bf16*)    (ws + 100663296);      // region C overlay
  float*    WkvTs    = (float*)   (ws + 117440512);      //  2,097,152 (x1024)
  bf16*     WoT      = (bf16*)    (ws + 119537664);      //  8,388,608
  float*    entriesF = (float*)   (ws + 127926272);      //  8,388,608
  float*    ckvF     = (float*)   (ws + 136314880);      //  1,048,576
  _Float16* ckh      = (_Float16*)(ws + 137363456);      //    262,144
  _Float16* ckl      = (_Float16*)(ws + 137625600);      //    262,144
  float*    wlog     = (float*)   (ws + 137887744);      //     16,384
  float*    wsm      = (float*)   (ws + 137904128);      //     16,384
  float*    bQ       = (float*)   (ws + 137920512);      //      8,192
  float*    bLKLV    = (float*)   (ws + 137928704);      //     16,384
  float*    bKV      = (float*)   (ws + 137945088);      //      1,024
  float*    bO       = (float*)   (ws + 137946112);      //      8,192
  _Float16* wqh      = (_Float16*)(ws + 137954304);      // region D (8,388,608)
  _Float16* wql      = (_Float16*)(ws + 146342912);      // region D (8,388,608)
  _Float16* ql       = (_Float16*)(ws + 137954304);      // region D overlay (16.7M)

  cvt_bias_k<<<dim3(8192), dim3(256), 0, stream>>>(hidden, hbf, bq, blk, blv, bk, bv, bo,
                                                   bQ, bLKLV, bKV, bO);
  transpose3_k<<<dim3(32, 32, 3), dim3(256), 0, stream>>>(Wlk, Wlv, Wo, bt_lklv, WoT);
  trans_f32s_kv<<<dim3(2, 32, 2), dim3(256), 0, stream>>>(Wk, Wv, WkvTs);

  wlog_k<<<dim3(1024), dim3(256), 0, stream>>>(hidden, Wcmp, bcmp, wlog);
  wsm_k<<<dim3(4), dim3(256), 0, stream>>>(wlog, wsm);
  entries_k<<<dim3(8192), dim3(256), 0, stream>>>(hidden, wsm, entriesF);

  // lk|lv projection first (consumes hbf + bt_lklv, freeing both regions)
  gemm_bt<bf16><<<dim3(32, 32), dim3(256), 0, stream>>>(hbf, bt_lklv, bLKLV, lklv, S_LEN, 4096, HID_, HID_);
  // small precise ckv projection (in-kernel split ok at this size)
  gemm_prec4<<<dim3(2, 8), dim3(256), 0, stream>>>(entriesF, WkvTs, bKV, ckvF, C_, 256, HID_, HID_);

  // precise q projection: pre-split operands, global_load_lds staging
  split_q_k<<<dim3(8192), dim3(256), 0, stream>>>(hidden, hidh, hidl);
  trans_split_wq<<<dim3(32, 32), dim3(256), 0, stream>>>(Wq, wqh, wql);
  gemm_hl4<<<dim3(16, 32), dim3(256), 0, stream>>>(hidh, hidl, wqh, wql, bQ, qf, S_LEN, HID_, HID_, HID_);

  // norms + rope (q: trig shared across heads, fp16 split fused; qh/ql overlay dead regions)
  normrope64_q<<<dim3(4096), dim3(256), 0, stream>>>(qf, qn_w, qh, ql);
  normrope64_ck<<<dim3(256), dim3(256), 0, stream>>>(ckvF, kn_w, ckh, ckl);
  normrope_bf_l<<<dim3(4096), dim3(256), 0, stream>>>(lklv, kn_w);

  // attention branches
  sparse_v9<<<dim3(512, 8), dim3(1024), 0, stream>>>(qh, ql, ckh, ckl, ckvF, sp);
  trans_v_k<<<dim3(64, 32), dim3(256), 0, stream>>>(lklv, VT);
  local_mfma<<<dim3(128, 16), dim3(128), 0, stream>>>(qf, lklv, VT, sp, merged);

  // output projection
  gemm_bt<float><<<dim3(16, 32), dim3(256), 0, stream>>>(merged, WoT, bO, out, S_LEN, HID_, HID_, HID_);
}

// Round 9
// 997.659 us; speedup vs baseline: 1.2228x; 1.0429x over previous
//
#include <hip/hip_runtime.h>
#include <hip/hip_bf16.h>
#include <hip/hip_fp16.h>
#include <stdint.h>

typedef __hip_bfloat16 bf16;
using bf16x8 = __attribute__((ext_vector_type(8))) short;     // 8 bf16
using half8  = __attribute__((ext_vector_type(8))) _Float16;  // 8 fp16
using f32x4  = __attribute__((ext_vector_type(4))) float;

#define S_LEN   4096
#define HID_    2048
#define NH_     16
#define D_      128
#define C_      1024
#define SCALE_  0.08838834764831845f   // 1/sqrt(128)
#define DESC_   (1.0 / 1048576.0)      // 2^-20 (undo ×1024 on both operands)

__device__ __forceinline__ void storeC(float* p, float v) { *p = v; }
__device__ __forceinline__ void storeC(bf16* p, float v)  { *p = __float2bfloat16(v); }
__device__ __forceinline__ void split2(float x, _Float16& h, _Float16& l) {
  h = (_Float16)x; l = (_Float16)(x - (float)h);
}
__device__ __forceinline__ short bf2s(bf16 b) { short s; __builtin_memcpy(&s, &b, 2); return s; }

#define GLDS(src, dst) __builtin_amdgcn_global_load_lds( \
    (const __attribute__((address_space(1))) void*)(src), \
    (__attribute__((address_space(3))) void*)(dst), 16, 0, 0)

// ================= device bodies (verbatim arithmetic from R7 kernels) =================

__device__ __forceinline__ void cvt_bias_body(int bxx, const float* __restrict__ src, bf16* __restrict__ dst,
                                              const float* bq, const float* blk, const float* blv,
                                              const float* bk, const float* bv, const float* bo,
                                              float* bQ, float* bLKLV, float* bKV, float* bO) {
  int i = (bxx * 256 + threadIdx.x) * 4;
  float4 v = *(const float4*)(src + i);
  bf16 o[4] = {__float2bfloat16(v.x), __float2bfloat16(v.y),
               __float2bfloat16(v.z), __float2bfloat16(v.w)};
  *(uint2*)(dst + i) = *(uint2*)o;
  int ib = bxx * 256 + threadIdx.x;
  if (ib < 8448) {
    if (ib < 2048)      bQ[ib] = bq[ib];
    else if (ib < 6144) { int j = ib - 2048; bLKLV[j] = (j < 2048) ? blk[j] : blv[j - 2048]; }
    else if (ib < 6400) { int j = ib - 6144; bKV[j] = (j < 128) ? bk[j] : bv[j - 128]; }
    else                bO[ib - 6400] = bo[ib - 6400];
  }
}

__device__ __forceinline__ void transpose3_body(int bxx, int byy, int bzz, char* smem,
                                                const float* __restrict__ Wlk, const float* __restrict__ Wlv,
                                                const float* __restrict__ Wo,
                                                bf16* __restrict__ bt_lklv, bf16* __restrict__ WoT) {
  float (*tile)[65] = (float(*)[65])smem;
  const float* src = (bzz == 0) ? Wlk : (bzz == 1) ? Wlv : Wo;
  bf16* dst = (bzz == 0) ? bt_lklv
            : (bzz == 1) ? (bt_lklv + (size_t)2048 * HID_) : WoT;
  const int c0 = bxx * 64, r0 = byy * 64;
  const int t = threadIdx.x, cc = t & 63, rb = t >> 6;
#pragma unroll
  for (int i = 0; i < 16; ++i) {
    int r = rb + i * 4;
    tile[r][cc] = src[(size_t)(r0 + r) * HID_ + c0 + cc];
  }
  __syncthreads();
#pragma unroll
  for (int i = 0; i < 16; ++i) {
    int r = rb + i * 4;
    dst[(size_t)(c0 + r) * HID_ + r0 + cc] = __float2bfloat16(tile[cc][r]);
  }
}

__device__ __forceinline__ void trans_kv_body(int bxx, int byy, int bzz, char* smem,
                                              const float* __restrict__ Wk, const float* __restrict__ Wv,
                                              float* __restrict__ WkvTs) {
  float (*tile)[65] = (float(*)[65])smem;
  const float* src = bzz ? Wv : Wk;
  float* dst = WkvTs + (bzz ? (size_t)128 * HID_ : 0);
  const int c0 = bxx * 64, r0 = byy * 64;
  const int t = threadIdx.x, cc = t & 63, rb = t >> 6;
#pragma unroll
  for (int i = 0; i < 16; ++i) {
    int r = rb + i * 4;
    tile[r][cc] = src[(size_t)(r0 + r) * 128 + c0 + cc];
  }
  __syncthreads();
#pragma unroll
  for (int i = 0; i < 16; ++i) {
    int r = rb + i * 4;
    dst[(size_t)(c0 + r) * HID_ + r0 + cc] = tile[cc][r] * 1024.0f;
  }
}

__device__ __forceinline__ void wlog_body(int bxx, const float* __restrict__ hidden,
                                          const float* __restrict__ wcmp, const float* __restrict__ bcmp,
                                          float* __restrict__ wlog) {
  int s = bxx * 4 + (threadIdx.x >> 6);
  int lane = threadIdx.x & 63;
  const float* hp = hidden + (size_t)s * HID_;
  double acc = 0.0;
  for (int i = lane; i < HID_; i += 64)
    acc += (double)hp[i] * (double)wcmp[i];
#pragma unroll
  for (int m = 32; m; m >>= 1) acc += __shfl_xor(acc, m, 64);
  if (lane == 0) wlog[s] = (float)(acc + (double)bcmp[0]);
}

__device__ __forceinline__ void split_q_body(int bxx, const float* __restrict__ src,
                                             _Float16* __restrict__ oh, _Float16* __restrict__ ol) {
  int i = (bxx * 256 + threadIdx.x) * 4;
  float4 v = *(const float4*)(src + i);
  float xs[4] = {v.x, v.y, v.z, v.w};
  _Float16 hh[4], ll[4];
#pragma unroll
  for (int e = 0; e < 4; ++e) split2(xs[e] * 1024.0f, hh[e], ll[e]);
  *(uint2*)(oh + i) = *(uint2*)hh;
  *(uint2*)(ol + i) = *(uint2*)ll;
}

__device__ __forceinline__ void trans_split_wq_body(int bxx, int byy, char* smem,
                                                    const float* __restrict__ src,
                                                    _Float16* __restrict__ oh, _Float16* __restrict__ ol) {
  float (*tile)[65] = (float(*)[65])smem;
  const int c0 = bxx * 64, r0 = byy * 64;
  const int t = threadIdx.x, cc = t & 63, rb = t >> 6;
#pragma unroll
  for (int i = 0; i < 16; ++i) {
    int r = rb + i * 4;
    tile[r][cc] = src[(size_t)(r0 + r) * HID_ + c0 + cc];
  }
  __syncthreads();
#pragma unroll
  for (int i = 0; i < 16; ++i) {
    int r = rb + i * 4;
    float x = tile[cc][r] * 1024.0f;
    _Float16 h, l; split2(x, h, l);
    size_t off = (size_t)(c0 + r) * HID_ + r0 + cc;
    oh[off] = h; ol[off] = l;
  }
}

__device__ __forceinline__ void entries_body(int bxx, const float* __restrict__ hidden,
                                             const float* __restrict__ wsm, float* __restrict__ entriesF) {
  int idx = bxx * 256 + threadIdx.x;
  int c = idx >> 11, hcol = idx & 2047;
  double e = 0.0;
#pragma unroll
  for (int r = 0; r < 4; ++r)
    e += (double)wsm[4 * c + r] * (double)hidden[(size_t)(4 * c + r) * HID_ + hcol];
  entriesF[idx] = (float)e;
}

template <typename OutT>
__device__ __forceinline__ void gemm_bt_body(int bxp, int byp, bf16* As, bf16* Bs,
                                             const bf16* __restrict__ A, const bf16* __restrict__ BT,
                                             const float* __restrict__ bias, OutT* __restrict__ Cmat,
                                             int M, int N, int K, int lda) {
  const int t = threadIdx.x;
  const int wave = t >> 6, lane = t & 63;
  const int wr = wave >> 1, wc = wave & 1;
  const int quad = lane >> 4, l15 = lane & 15;
  const int bx = bxp * 128, by = byp * 128;
  const int srow = t >> 2, scol = (t & 3) * 8;
  f32x4 acc[4][4] = {};
  const bf16* a0 = A + (size_t)(by + srow) * lda + scol;
  const bf16* a1 = A + (size_t)(by + 64 + srow) * lda + scol;
  const bf16* b0 = BT + (size_t)(bx + srow) * K + scol;
  const bf16* b1 = BT + (size_t)(bx + 64 + srow) * K + scol;
  for (int k0 = 0; k0 < K; k0 += 32) {
    GLDS(a0 + k0, As + t * 8);
    GLDS(a1 + k0, As + 2048 + t * 8);
    GLDS(b0 + k0, Bs + t * 8);
    GLDS(b1 + k0, Bs + 2048 + t * 8);
    __syncthreads();
    bf16x8 aF[4], bF[4];
#pragma unroll
    for (int i = 0; i < 4; ++i)
      aF[i] = *(const bf16x8*)(As + (wr * 64 + i * 16 + l15) * 32 + quad * 8);
#pragma unroll
    for (int j = 0; j < 4; ++j)
      bF[j] = *(const bf16x8*)(Bs + (wc * 64 + j * 16 + l15) * 32 + quad * 8);
#pragma unroll
    for (int i = 0; i < 4; ++i)
#pragma unroll
      for (int j = 0; j < 4; ++j)
        acc[i][j] = __builtin_amdgcn_mfma_f32_16x16x32_bf16(aF[i], bF[j], acc[i][j], 0, 0, 0);
    __syncthreads();
  }
#pragma unroll
  for (int i = 0; i < 4; ++i)
#pragma unroll
    for (int j = 0; j < 4; ++j)
#pragma unroll
      for (int r = 0; r < 4; ++r) {
        int row = by + wr * 64 + i * 16 + quad * 4 + r;
        int col = bx + wc * 64 + j * 16 + l15;
        storeC(&Cmat[(size_t)row * N + col], acc[i][j][r] + bias[col]);
      }
}

__device__ __forceinline__ void gemm_hl4_body(int bxp, int byp, _Float16* Ahs, _Float16* Als,
                                              _Float16* Bhs, _Float16* Bls,
                                              const _Float16* __restrict__ Ah, const _Float16* __restrict__ Al,
                                              const _Float16* __restrict__ Bh, const _Float16* __restrict__ Bl,
                                              const float* __restrict__ bias, float* __restrict__ Cmat,
                                              int M, int N, int K, int lda) {
  const int t = threadIdx.x;
  const int wave = t >> 6, lane = t & 63;
  const int wr = wave >> 1, wc = wave & 1;
  const int quad = lane >> 4, l15 = lane & 15;
  const int bx = bxp * 128, by = byp * 128;
  const int srow = t >> 2, scol = (t & 3) * 8;
  double acc[4][4][4] = {};
  const _Float16* a0h = Ah + (size_t)(by + srow) * lda + scol;
  const _Float16* a1h = Ah + (size_t)(by + 64 + srow) * lda + scol;
  const _Float16* a0l = Al + (size_t)(by + srow) * lda + scol;
  const _Float16* a1l = Al + (size_t)(by + 64 + srow) * lda + scol;
  const _Float16* b0h = Bh + (size_t)(bx + srow) * K + scol;
  const _Float16* b1h = Bh + (size_t)(bx + 64 + srow) * K + scol;
  const _Float16* b0l = Bl + (size_t)(bx + srow) * K + scol;
  const _Float16* b1l = Bl + (size_t)(bx + 64 + srow) * K + scol;
  for (int k0 = 0; k0 < K; k0 += 32) {
    GLDS(a0h + k0, Ahs + t * 8);
    GLDS(a1h + k0, Ahs + 2048 + t * 8);
    GLDS(a0l + k0, Als + t * 8);
    GLDS(a1l + k0, Als + 2048 + t * 8);
    GLDS(b0h + k0, Bhs + t * 8);
    GLDS(b1h + k0, Bhs + 2048 + t * 8);
    GLDS(b0l + k0, Bls + t * 8);
    GLDS(b1l + k0, Bls + 2048 + t * 8);
    __syncthreads();
    half8 aFh[4], aFl[4], bFh[4], bFl[4];
#pragma unroll
    for (int i = 0; i < 4; ++i) {
      int ro = (wr * 64 + i * 16 + l15) * 32 + quad * 8;
      aFh[i] = *(const half8*)(Ahs + ro);
      aFl[i] = *(const half8*)(Als + ro);
    }
#pragma unroll
    for (int j = 0; j < 4; ++j) {
      int ro = (wc * 64 + j * 16 + l15) * 32 + quad * 8;
      bFh[j] = *(const half8*)(Bhs + ro);
      bFl[j] = *(const half8*)(Bls + ro);
    }
#pragma unroll
    for (int i = 0; i < 4; ++i)
#pragma unroll
      for (int j = 0; j < 4; ++j) {
        f32x4 tt = {0.f, 0.f, 0.f, 0.f};
        tt = __builtin_amdgcn_mfma_f32_16x16x32_f16(aFl[i], bFl[j], tt, 0, 0, 0);
        tt = __builtin_amdgcn_mfma_f32_16x16x32_f16(aFl[i], bFh[j], tt, 0, 0, 0);
        tt = __builtin_amdgcn_mfma_f32_16x16x32_f16(aFh[i], bFl[j], tt, 0, 0, 0);
        tt = __builtin_amdgcn_mfma_f32_16x16x32_f16(aFh[i], bFh[j], tt, 0, 0, 0);
#pragma unroll
        for (int r = 0; r < 4; ++r) acc[i][j][r] += (double)tt[r];
      }
    __syncthreads();
  }
#pragma unroll
  for (int i = 0; i < 4; ++i)
#pragma unroll
    for (int j = 0; j < 4; ++j)
#pragma unroll
      for (int r = 0; r < 4; ++r) {
        int row = by + wr * 64 + i * 16 + quad * 4 + r;
        int col = bx + wc * 64 + j * 16 + l15;
        Cmat[(size_t)row * N + col] = (float)(acc[i][j][r] * DESC_ + (double)bias[col]);
      }
}

__device__ __forceinline__ void gemm_prec4_body(int bxp, int byp, _Float16* Ah, _Float16* Al,
                                                _Float16* Bh, _Float16* Bl,
                                                const float* __restrict__ A, const float* __restrict__ BT,
                                                const float* __restrict__ bias, float* __restrict__ Cmat,
                                                int M, int N, int K, int lda) {
  const int t = threadIdx.x;
  const int wave = t >> 6, lane = t & 63;
  const int wr = wave >> 1, wc = wave & 1;
  const int quad = lane >> 4, l15 = lane & 15;
  const int bx = bxp * 128, by = byp * 128;
  double acc[4][4][4] = {};
  for (int k0 = 0; k0 < K; k0 += 32) {
#pragma unroll
    for (int it = 0; it < 4; ++it) {
      int sl = t + it * 256;
      int isB = sl >> 9, s2 = sl & 511, r = s2 >> 2, g = s2 & 3;
      const float* src = isB ? (BT + (size_t)(bx + r) * K + k0 + g * 8)
                             : (A  + (size_t)(by + r) * lda + k0 + g * 8);
      float4 u = ((const float4*)src)[0];
      float4 v = ((const float4*)src)[1];
      float xs[8] = {u.x, u.y, u.z, u.w, v.x, v.y, v.z, v.w};
      half8 hh, ll;
#pragma unroll
      for (int e = 0; e < 8; ++e) {
        float x = isB ? xs[e] : xs[e] * 1024.0f;
        _Float16 h, l; split2(x, h, l);
        hh[e] = h; ll[e] = l;
      }
      _Float16* dh = (isB ? Bh : Ah) + r * 32 + g * 8;
      _Float16* dl = (isB ? Bl : Al) + r * 32 + g * 8;
      *(half8*)dh = hh;
      *(half8*)dl = ll;
    }
    __syncthreads();
    half8 aFh[4], aFl[4], bFh[4], bFl[4];
#pragma unroll
    for (int i = 0; i < 4; ++i) {
      int ro = (wr * 64 + i * 16 + l15) * 32 + quad * 8;
      aFh[i] = *(const half8*)(Ah + ro);
      aFl[i] = *(const half8*)(Al + ro);
    }
#pragma unroll
    for (int j = 0; j < 4; ++j) {
      int ro = (wc * 64 + j * 16 + l15) * 32 + quad * 8;
      bFh[j] = *(const half8*)(Bh + ro);
      bFl[j] = *(const half8*)(Bl + ro);
    }
#pragma unroll
    for (int i = 0; i < 4; ++i)
#pragma unroll
      for (int j = 0; j < 4; ++j) {
        f32x4 tt = {0.f, 0.f, 0.f, 0.f};
        tt = __builtin_amdgcn_mfma_f32_16x16x32_f16(aFl[i], bFl[j], tt, 0, 0, 0);
        tt = __builtin_amdgcn_mfma_f32_16x16x32_f16(aFl[i], bFh[j], tt, 0, 0, 0);
        tt = __builtin_amdgcn_mfma_f32_16x16x32_f16(aFh[i], bFl[j], tt, 0, 0, 0);
        tt = __builtin_amdgcn_mfma_f32_16x16x32_f16(aFh[i], bFh[j], tt, 0, 0, 0);
#pragma unroll
        for (int r = 0; r < 4; ++r) acc[i][j][r] += (double)tt[r];
      }
    __syncthreads();
  }
#pragma unroll
  for (int i = 0; i < 4; ++i)
#pragma unroll
    for (int j = 0; j < 4; ++j)
#pragma unroll
      for (int r = 0; r < 4; ++r) {
        int row = by + wr * 64 + i * 16 + quad * 4 + r;
        int col = bx + wc * 64 + j * 16 + l15;
        Cmat[(size_t)row * N + col] = (float)(acc[i][j][r] * DESC_ + (double)bias[col]);
      }
}

__device__ __forceinline__ void normrope_q_body(int s, double* csd, double* snd,
                                                float* __restrict__ base, const float* __restrict__ w,
                                                _Float16* __restrict__ qh, _Float16* __restrict__ ql) {
  const int t = threadIdx.x, wv = t >> 6, lane = t & 63;
  if (t < 32) {
    float invf = 1.0f / (float)pow(10000.0, (double)t * (1.0 / 32.0));
    float angf = (float)s * invf;
    double ang = (double)angf;
    csd[t] = cos(ang);
    snd[t] = sin(ang);
  }
  __syncthreads();
  const int fi = lane & 31;
  float* ps = base + (size_t)s * HID_;
  for (int h = wv; h < 16; h += 4) {
    float* p = ps + h * 128;
    double x0 = (double)p[lane];
    double x1 = (double)p[lane + 64];
    double ss = x0 * x0 + x1 * x1;
#pragma unroll
    for (int m = 32; m; m >>= 1) ss += __shfl_xor(ss, m, 64);
    double rstd = 1.0 / sqrt(ss * (1.0 / 128.0) + 1e-6);
    double n0 = x0 * rstd * (double)w[lane];
    double n1 = x1 * rstd * (double)w[lane + 64];
    double other = __shfl_xor(n0, 32, 64);
    double cs = csd[fi], sn = snd[fi];
    double r0 = (lane < 32) ? (n0 * cs - other * sn) : (other * sn + n0 * cs);
    float f0 = (float)r0, f1 = (float)n1;
    p[lane] = f0;
    p[lane + 64] = f1;
    _Float16 h0, l0, h1, l1;
    split2(f0 * 1024.0f, h0, l0);
    split2(f1 * 1024.0f, h1, l1);
    size_t off = (size_t)s * HID_ + h * 128;
    qh[off + lane] = h0;       ql[off + lane] = l0;
    qh[off + 64 + lane] = h1;  ql[off + 64 + lane] = l1;
  }
}

__device__ __forceinline__ void normrope_ck_body(int bxx, float* __restrict__ base, const float* __restrict__ w,
                                                 _Float16* __restrict__ ckh, _Float16* __restrict__ ckl) {
  int row = bxx * 4 + (threadIdx.x >> 6);
  int lane = threadIdx.x & 63;
  float* p = base + (size_t)row * 256;
  double x0 = (double)p[lane];
  double x1 = (double)p[lane + 64];
  double ss = x0 * x0 + x1 * x1;
#pragma unroll
  for (int m = 32; m; m >>= 1) ss += __shfl_xor(ss, m, 64);
  double rstd = 1.0 / sqrt(ss * (1.0 / 128.0) + 1e-6);
  double n0 = x0 * rstd * (double)w[lane];
  double n1 = x1 * rstd * (double)w[lane + 64];
  double other = __shfl_xor(n0, 32, 64);
  int fi = lane & 31;
  float invf = 1.0f / (float)pow(10000.0, (double)fi * (1.0 / 32.0));
  float angf = (float)(row * 4 + 3) * invf;
  double ang = (double)angf;
  double cs = cos(ang), sn = sin(ang);
  double r0 = (lane < 32) ? (n0 * cs - other * sn) : (other * sn + n0 * cs);
  float f0 = (float)r0, f1 = (float)n1;
  p[lane] = f0;
  p[lane + 64] = f1;
  _Float16 h0, l0, h1, l1;
  split2(f0 * 1024.0f, h0, l0);
  split2(f1 * 1024.0f, h1, l1);
  ckh[row * 128 + lane] = h0;       ckl[row * 128 + lane] = l0;
  ckh[row * 128 + 64 + lane] = h1;  ckl[row * 128 + 64 + lane] = l1;
}

__device__ __forceinline__ void normrope_bfl_body(int s, float* csf, float* snf,
                                                  bf16* __restrict__ base, const float* __restrict__ w) {
  const int t = threadIdx.x, wv = t >> 6, lane = t & 63;
  if (t < 32) {
    float invf = 1.0f / (float)pow(10000.0, (double)t * (1.0 / 32.0));
    float ang = (float)s * invf;
    csf[t] = cosf(ang);
    snf[t] = sinf(ang);
  }
  __syncthreads();
  const int fi = lane & 31;
  bf16* ps = base + (size_t)s * 4096;
  for (int h = wv; h < 16; h += 4) {
    bf16* p = ps + h * 128;
    float x0 = __bfloat162float(p[lane]);
    float x1 = __bfloat162float(p[lane + 64]);
    float ss = x0 * x0 + x1 * x1;
#pragma unroll
    for (int m = 32; m; m >>= 1) ss += __shfl_xor(ss, m, 64);
    float rstd = rsqrtf(ss * 0.0078125f + 1e-6f);
    float n0 = x0 * rstd * w[lane];
    float n1 = x1 * rstd * w[lane + 64];
    float other = __shfl_xor(n0, 32, 64);
    float cs = csf[fi], sn = snf[fi];
    float r0 = (lane < 32) ? (n0 * cs - other * sn) : (other * sn + n0 * cs);
    p[lane] = __float2bfloat16(r0);
    p[lane + 64] = __float2bfloat16(n1);
  }
}

// ================= fused launches =================

// [transpose3: 0..3071][kv: 3072..3199][cvt_bias: 3200..11391][wlog: 11392..12415]
__global__ __launch_bounds__(256) void prep_fused(const float* hidden, bf16* hbf,
                                                  const float* Wlk, const float* Wlv, const float* Wo,
                                                  bf16* bt_lklv, bf16* WoT,
                                                  const float* Wk, const float* Wv, float* WkvTs,
                                                  const float* wcmp, const float* bcmp, float* wlog,
                                                  const float* bq, const float* blk, const float* blv,
                                                  const float* bk, const float* bv, const float* bo,
                                                  float* bQ, float* bLKLV, float* bKV, float* bO) {
  __shared__ __align__(16) char smem[16640];
  int b = blockIdx.x;
  if (b < 3072) {
    int z = b >> 10, rem = b & 1023;
    transpose3_body(rem & 31, rem >> 5, z, smem, Wlk, Wlv, Wo, bt_lklv, WoT);
  } else if (b < 3200) {
    int tt = b - 3072;
    trans_kv_body(tt & 1, (tt & 63) >> 1, tt >> 6, smem, Wk, Wv, WkvTs);
  } else if (b < 11392) {
    cvt_bias_body(b - 3200, hidden, hbf, bq, blk, blv, bk, bv, bo, bQ, bLKLV, bKV, bO);
  } else {
    wlog_body(b - 11392, hidden, wcmp, bcmp, wlog);
  }
}

__global__ void wsm_k(const float* __restrict__ wlog, float* __restrict__ wsm) {
  int c = blockIdx.x * 256 + threadIdx.x;
  if (c >= C_) return;
  double v[4], m = -1e300;
#pragma unroll
  for (int r = 0; r < 4; ++r) { v[r] = (double)wlog[4 * c + r]; if (v[r] > m) m = v[r]; }
  double sum = 0.0;
#pragma unroll
  for (int r = 0; r < 4; ++r) { v[r] = exp(v[r] - m); sum += v[r]; }
#pragma unroll
  for (int r = 0; r < 4; ++r) wsm[4 * c + r] = (float)(v[r] / sum);
}

// [gemm_bt lklv: 0..1023][entries: 1024..9215]
__global__ __launch_bounds__(256) void lklv_entries_fused(const bf16* hbf, const bf16* bt_lklv,
                                                          const float* bLKLV, bf16* lklv,
                                                          const float* hidden, const float* wsm,
                                                          float* entriesF) {
  __shared__ __align__(16) bf16 AsBs[2][4096];
  int b = blockIdx.x;
  if (b < 1024) {
    gemm_bt_body<bf16>(b & 31, b >> 5, AsBs[0], AsBs[1], hbf, bt_lklv, bLKLV, lklv,
                       S_LEN, 4096, HID_, HID_);
  } else {
    entries_body(b - 1024, hidden, wsm, entriesF);
  }
}

// [trans_split_wq: 0..1023][split_q: 1024..9215]
__global__ __launch_bounds__(256) void splitq_fused(const float* hidden, _Float16* hidh, _Float16* hidl,
                                                    const float* Wq, _Float16* wqh, _Float16* wql) {
  __shared__ __align__(16) char smem[16640];
  int b = blockIdx.x;
  if (b < 1024) {
    trans_split_wq_body(b & 31, b >> 5, smem, Wq, wqh, wql);
  } else {
    split_q_body(b - 1024, hidden, hidh, hidl);
  }
}

// [gemm_hl4: 0..511][gemm_prec4 ckv: 512..527]
__global__ __launch_bounds__(256) void qgemm_fused(const _Float16* hidh, const _Float16* hidl,
                                                   const _Float16* wqh, const _Float16* wql,
                                                   const float* bQ, float* qf,
                                                   const float* entriesF, const float* WkvTs,
                                                   const float* bKV, float* ckvF) {
  __shared__ __align__(16) _Float16 SH4[4][4096];
  int b = blockIdx.x;
  if (b < 512) {
    gemm_hl4_body(b & 15, b >> 4, SH4[0], SH4[1], SH4[2], SH4[3],
                  hidh, hidl, wqh, wql, bQ, qf, S_LEN, HID_, HID_, HID_);
  } else {
    int tt = b - 512;
    gemm_prec4_body(tt & 1, tt >> 1, SH4[0], SH4[1], SH4[2], SH4[3],
                    entriesF, WkvTs, bKV, ckvF, C_, 256, HID_, HID_);
  }
}

// [normrope_ck: 0..255][normrope_q: 256..4351][normrope_bfl: 4352..8447]
__global__ __launch_bounds__(256) void normrope_fused(float* qf, const float* qn_w,
                                                      _Float16* qh, _Float16* ql,
                                                      float* ckvF, const float* kn_w,
                                                      _Float16* ckh, _Float16* ckl,
                                                      bf16* lklv) {
  __shared__ double csd[32], snd[32];
  __shared__ float csf[32], snf[32];
  int b = blockIdx.x;
  if (b < 256) {
    normrope_ck_body(b, ckvF, kn_w, ckh, ckl);
  } else if (b < 4352) {
    normrope_q_body(b - 256, csd, snd, qf, qn_w, qh, ql);
  } else {
    normrope_bfl_body(b - 4352, csf, snf, lklv, kn_w);
  }
}

// ---------------- transpose lv half of lklv -> VT [2048][4096] ----------------
__global__ __launch_bounds__(256) void trans_v_k(const bf16* __restrict__ lklv, bf16* __restrict__ VT) {
  __shared__ ushort tile[64][65];
  const int s0 = blockIdx.x * 64, c0 = blockIdx.y * 64;
  const int t = threadIdx.x, cc = t & 63, rb = t >> 6;
  const ushort* src = (const ushort*)lklv;
#pragma unroll
  for (int i = 0; i < 16; ++i) {
    int r = rb + i * 4;
    tile[r][cc] = src[(size_t)(s0 + r) * 4096 + 2048 + c0 + cc];
  }
  __syncthreads();
  ushort* dst = (ushort*)VT;
#pragma unroll
  for (int i = 0; i < 16; ++i) {
    int r = rb + i * 4;
    dst[(size_t)(c0 + r) * 4096 + s0 + cc] = tile[cc][r];
  }
}

// ---------------- out projection (standalone gemm_bt wrapper) ----------------
template <typename OutT>
__global__ __launch_bounds__(256) void gemm_bt(const bf16* __restrict__ A, const bf16* __restrict__ BT,
                                               const float* __restrict__ bias, OutT* __restrict__ Cmat,
                                               int M, int N, int K, int lda) {
  __shared__ __align__(16) bf16 AsBs[2][4096];
  gemm_bt_body<OutT>(blockIdx.x, blockIdx.y, AsBs[0], AsBs[1], A, BT, bias, Cmat, M, N, K, lda);
}

// ---------------- sparse v9 (verbatim) ----------------
__global__ __launch_bounds__(1024, 8) void sparse_v9(const _Float16* __restrict__ qh, const _Float16* __restrict__ ql,
                                                     const _Float16* __restrict__ ckh, const _Float16* __restrict__ ckl,
                                                     const float* __restrict__ ckvF, bf16* __restrict__ sp) {
  __shared__ float sc[16 * 1024];               // 64 KB -> 2 blocks/CU
  const int by = blockIdx.y;
  const int s0 = blockIdx.x * 8;
  const int t = threadIdx.x, w = t >> 6, lane = t & 63;
  const int quad = lane >> 4, l15 = lane & 15;
  const int nvmax  = (s0 >> 2) + 2;
  const int ntiles = (nvmax + 15) >> 4;
  const double esc = (double)SCALE_ * DESC_;

  if (w < ntiles) {
    const int sA = s0 + (l15 & 7);
    const int hA = 2 * by + (l15 >> 3);
    half8 aFh[4], aFl[4];
    {
      const _Float16* qbh = qh + (size_t)sA * HID_ + hA * 128 + quad * 8;
      const _Float16* qbl = ql + (size_t)sA * HID_ + hA * 128 + quad * 8;
#pragma unroll
      for (int kk = 0; kk < 4; ++kk) {
        aFh[kk] = *(const half8*)(qbh + kk * 32);
        aFl[kk] = *(const half8*)(qbl + kk * 32);
      }
    }
    for (int ct = w; ct < ntiles; ct += 16) {
      const int c0 = ct * 16;
      const _Float16* kbh = ckh + (size_t)(c0 + l15) * 128 + quad * 8;
      const _Float16* kbl = ckl + (size_t)(c0 + l15) * 128 + quad * 8;
      double a64[4] = {0.0, 0.0, 0.0, 0.0};
#pragma unroll
      for (int kk = 0; kk < 4; ++kk) {
        half8 bh = *(const half8*)(kbh + kk * 32);
        half8 bl = *(const half8*)(kbl + kk * 32);
        f32x4 tt = {0.f, 0.f, 0.f, 0.f};
        tt = __builtin_amdgcn_mfma_f32_16x16x32_f16(aFl[kk], bl, tt, 0, 0, 0);
        tt = __builtin_amdgcn_mfma_f32_16x16x32_f16(aFl[kk], bh, tt, 0, 0, 0);
        tt = __builtin_amdgcn_mfma_f32_16x16x32_f16(aFh[kk], bl, tt, 0, 0, 0);
        tt = __builtin_amdgcn_mfma_f32_16x16x32_f16(aFh[kk], bh, tt, 0, 0, 0);
#pragma unroll
        for (int r = 0; r < 4; ++r) a64[r] += (double)tt[r];
      }
#pragma unroll
      for (int r = 0; r < 4; ++r)
        sc[(quad * 4 + r) * 1024 + c0 + l15] = (float)(a64[r] * esc);
    }
  }
  __syncthreads();
  if (w >= 4) return;

  const int q = w * 4 + quad;
  const int p2 = q >> 3, wq = q & 7;
  const int s = s0 + wq;
  const int nv = (s >= 3) ? (((s - 3) >> 2) + 1) : 0;
  const float* srow = sc + q * 1024;
  const int jmaxB = (nvmax + 63) >> 6;

  float tv0 = -1e38f, tv1 = -1e38f, tv2 = -1e38f, tv3 = -1e38f;
  int   ti0 = 0x40000000, ti1 = 0x40000000, ti2 = 0x40000000, ti3 = 0x40000000;
  for (int j = 0; j < jmaxB; ++j) {
    int cb = j * 64 + l15 * 4;
    float4 vv = *(const float4*)(srow + cb);
    float xs[4] = {vv.x, vv.y, vv.z, vv.w};
#pragma unroll
    for (int e = 0; e < 4; ++e) {
      int c = cb + e;
      float v = (c < nv) ? xs[e] : -1e38f;
      if (v > tv3) {
        if (v > tv0)      { tv3=tv2;ti3=ti2; tv2=tv1;ti2=ti1; tv1=tv0;ti1=ti0; tv0=v;ti0=c; }
        else if (v > tv1) { tv3=tv2;ti3=ti2; tv2=tv1;ti2=ti1; tv1=v;ti1=c; }
        else if (v > tv2) { tv3=tv2;ti3=ti2; tv2=v;ti2=c; }
        else              { tv3=v;ti3=c; }
      }
    }
  }

  unsigned long long deadm = 0ull;
  int ncons = 0;
  float bvs[8]; int bis[8];
#pragma unroll
  for (int it = 0; it < 8; ++it) {
    float bv = tv0; int bi = ti0;
#pragma unroll
    for (int mm = 1; mm <= 8; mm <<= 1) {
      float ov = __shfl_xor(bv, mm, 64);
      int   oi = __shfl_xor(bi, mm, 64);
      if (ov > bv || (ov == bv && oi < bi)) { bv = ov; bi = oi; }
    }
    bvs[it] = bv; bis[it] = bi;
    if (bv > -1e29f && (((bi >> 2) & 15) == l15)) {
      deadm |= 1ull << (((bi >> 6) << 2) | (bi & 3));
      tv0=tv1;ti0=ti1; tv1=tv2;ti1=ti2; tv2=tv3;ti2=ti3;
      tv3=-1e38f; ti3=0x40000000;
      if (++ncons == 4) {
        ncons = 0;
        tv0=tv1=tv2=tv3=-1e38f;
        ti0=ti1=ti2=ti3=0x40000000;
        for (int j = 0; j < jmaxB; ++j) {
          int cb = j * 64 + l15 * 4;
          float4 vv = *(const float4*)(srow + cb);
          float xs[4] = {vv.x, vv.y, vv.z, vv.w};
#pragma unroll
          for (int e = 0; e < 4; ++e) {
            int c = cb + e;
            int li = ((c >> 6) << 2) | (c & 3);
            float v = (c < nv && !((deadm >> li) & 1ull)) ? xs[e] : -1e38f;
            if (v > tv3) {
              if (v > tv0)      { tv3=tv2;ti3=ti2; tv2=tv1;ti2=ti1; tv1=tv0;ti1=ti0; tv0=v;ti0=c; }
              else if (v > tv1) { tv3=tv2;ti3=ti2; tv2=tv1;ti2=ti1; tv1=v;ti1=c; }
              else if (v > tv2) { tv3=tv2;ti3=ti2; tv2=v;ti2=c; }
              else              { tv3=v;ti3=c; }
            }
          }
        }
      }
    }
  }

  const float m0 = bvs[0];
  float a0=0.f,a1=0.f,a2=0.f,a3=0.f,a4=0.f,a5=0.f,a6=0.f,a7=0.f;
  float esum = 0.f;
#pragma unroll
  for (int it = 0; it < 8; ++it) {
    if (bvs[it] > -1e29f) {
      float wgt = expf(bvs[it] - m0);
      esum += wgt;
      const float* cvp = ckvF + (size_t)bis[it] * 256 + 128 + l15 * 8;
      float4 u = *(const float4*)cvp;
      float4 v = *(const float4*)(cvp + 4);
      a0 += wgt*u.x; a1 += wgt*u.y; a2 += wgt*u.z; a3 += wgt*u.w;
      a4 += wgt*v.x; a5 += wgt*v.y; a6 += wgt*v.z; a7 += wgt*v.w;
    }
  }
  float inv = 1.0f / fmaxf(esum, 1e-9f);
  bf16* op = sp + (size_t)s * 2048 + (2 * by + p2) * 128 + l15 * 8;
  bf16 ob[8] = {__float2bfloat16(a0*inv), __float2bfloat16(a1*inv),
                __float2bfloat16(a2*inv), __float2bfloat16(a3*inv),
                __float2bfloat16(a4*inv), __float2bfloat16(a5*inv),
                __float2bfloat16(a6*inv), __float2bfloat16(a7*inv)};
  *(uint4*)op = *(uint4*)ob;
}

// ---------------- local sliding-window via MFMA (verbatim) ----------------
__global__ __launch_bounds__(128) void local_mfma(const float* __restrict__ qf,
                                                  const bf16* __restrict__ lklv,
                                                  const bf16* __restrict__ VT,
                                                  const bf16* __restrict__ sp,
                                                  bf16* __restrict__ merged) {
  constexpr int PADP = 168;
  __shared__ bf16 PhS[2][16 * PADP];
  __shared__ bf16 PlS[2][16 * PADP];
  const int h = blockIdx.y;
  const int t = threadIdx.x, w = t >> 6, lane = t & 63;
  const int quad = lane >> 4, l15 = lane & 15;
  const int sw = blockIdx.x * 32 + w * 16;
  const int kbase = sw - 128;
  const int ridx = quad * 4;

  bf16x8 qH[4], qL[4];
  {
    const float* qp = qf + (size_t)(sw + l15) * HID_ + h * 128 + quad * 8;
#pragma unroll
    for (int kk = 0; kk < 4; ++kk) {
      float4 u = *(const float4*)(qp + kk * 32);
      float4 v = *(const float4*)(qp + kk * 32 + 4);
      float xs[8] = {u.x, u.y, u.z, u.w, v.x, v.y, v.z, v.w};
      bf16x8 hh, ll;
#pragma unroll
      for (int e = 0; e < 8; ++e) {
        bf16 bh = __float2bfloat16(xs[e]);
        float fh = __bfloat162float(bh);
        bf16 bl = __float2bfloat16(xs[e] - fh);
        hh[e] = bf2s(bh); ll[e] = bf2s(bl);
      }
      qH[kk] = hh; qL[kk] = ll;
    }
  }

  float sc[9][4];
#pragma unroll
  for (int ct = 0; ct < 9; ++ct) {
    int key0 = kbase + ct * 16 + l15;
    const bf16* kp = lklv + (size_t)(key0 < 0 ? 0 : key0) * 4096 + h * 128 + quad * 8;
    f32x4 acc = {0.f, 0.f, 0.f, 0.f};
#pragma unroll
    for (int kk = 0; kk < 4; ++kk) {
      bf16x8 kb = *(const bf16x8*)(kp + kk * 32);
      acc = __builtin_amdgcn_mfma_f32_16x16x32_bf16(qL[kk], kb, acc, 0, 0, 0);
      acc = __builtin_amdgcn_mfma_f32_16x16x32_bf16(qH[kk], kb, acc, 0, 0, 0);
    }
#pragma unroll
    for (int r = 0; r < 4; ++r) sc[ct][r] = acc[r] * SCALE_;
  }

  float mrow[4] = {-1e30f, -1e30f, -1e30f, -1e30f};
#pragma unroll
  for (int ct = 0; ct < 9; ++ct) {
    int cidx = ct * 16 + l15;
#pragma unroll
    for (int r = 0; r < 4; ++r) {
      bool valid = (cidx >= ridx + r) && (cidx <= ridx + r + 128) && (kbase + cidx >= 0);
      float v = valid ? sc[ct][r] : -1e30f;
      sc[ct][r] = v;
      mrow[r] = fmaxf(mrow[r], v);
    }
  }
#pragma unroll
  for (int mm = 1; mm <= 8; mm <<= 1)
#pragma unroll
    for (int r = 0; r < 4; ++r) mrow[r] = fmaxf(mrow[r], __shfl_xor(mrow[r], mm, 64));

  bf16* phb = &PhS[w][0];
  bf16* plb = &PlS[w][0];
  for (int z = lane; z < 256; z += 64) {
    int zr = z >> 4, zc = z & 15;
    phb[zr * PADP + 144 + zc] = __float2bfloat16(0.f);
    plb[zr * PADP + 144 + zc] = __float2bfloat16(0.f);
  }
  float lsum[4] = {0.f, 0.f, 0.f, 0.f};
#pragma unroll
  for (int ct = 0; ct < 9; ++ct) {
    int cidx = ct * 16 + l15;
#pragma unroll
    for (int r = 0; r < 4; ++r) {
      float e = (sc[ct][r] > -1e29f) ? expf(sc[ct][r] - mrow[r]) : 0.f;
      lsum[r] += e;
      bf16 bh = __float2bfloat16(e);
      float fh = __bfloat162float(bh);
      bf16 bl = __float2bfloat16(e - fh);
      phb[(ridx + r) * PADP + cidx] = bh;
      plb[(ridx + r) * PADP + cidx] = bl;
    }
  }
#pragma unroll
  for (int mm = 1; mm <= 8; mm <<= 1)
#pragma unroll
    for (int r = 0; r < 4; ++r) lsum[r] += __shfl_xor(lsum[r], mm, 64);
  float inv[4];
#pragma unroll
  for (int r = 0; r < 4; ++r) inv[r] = 1.0f / lsum[r];

  bf16x8 pH[5], pL[5];
#pragma unroll
  for (int kk = 0; kk < 5; ++kk) {
    pH[kk] = *(const bf16x8*)(phb + l15 * PADP + kk * 32 + quad * 8);
    pL[kk] = *(const bf16x8*)(plb + l15 * PADP + kk * 32 + quad * 8);
  }

#pragma unroll
  for (int dt = 0; dt < 8; ++dt) {
    const bf16* vrow = VT + (size_t)(h * 128 + dt * 16 + l15) * 4096;
    f32x4 acc = {0.f, 0.f, 0.f, 0.f};
#pragma unroll
    for (int kk = 0; kk < 5; ++kk) {
      int ko = kbase + kk * 32 + quad * 8;
      ko = ko < 0 ? 0 : (ko > 4088 ? 4088 : ko);
      bf16x8 vb = *(const bf16x8*)(vrow + ko);
      acc = __builtin_amdgcn_mfma_f32_16x16x32_bf16(pL[kk], vb, acc, 0, 0, 0);
      acc = __builtin_amdgcn_mfma_f32_16x16x32_bf16(pH[kk], vb, acc, 0, 0, 0);
    }
#pragma unroll
    for (int r = 0; r < 4; ++r) {
      int srow = sw + ridx + r;
      size_t off = (size_t)srow * 2048 + h * 128 + dt * 16 + l15;
      float spv = __bfloat162float(sp[off]);
      merged[off] = __float2bfloat16((acc[r] * inv[r] + spv) * 0.5f);
    }
  }
}

// ---------------- host orchestration ----------------
extern "C" void kernel_launch(void* const* d_in, const int* in_sizes, int n_in,
                              void* d_out, int out_size, void* d_ws, size_t ws_size,
                              hipStream_t stream) {
  (void)in_sizes; (void)n_in; (void)out_size; (void)ws_size;
  const float* hidden = (const float*)d_in[0];
  const float* Wq   = (const float*)d_in[1];
  const float* bq   = (const float*)d_in[2];
  const float* Wcmp = (const float*)d_in[3];
  const float* bcmp = (const float*)d_in[4];
  const float* Wk   = (const float*)d_in[5];
  const float* bk   = (const float*)d_in[6];
  const float* Wv   = (const float*)d_in[7];
  const float* bv   = (const float*)d_in[8];
  const float* Wlk  = (const float*)d_in[9];
  const float* blk  = (const float*)d_in[10];
  const float* Wlv  = (const float*)d_in[11];
  const float* blv  = (const float*)d_in[12];
  const float* qn_w = (const float*)d_in[13];
  const float* kn_w = (const float*)d_in[14];
  const float* Wo   = (const float*)d_in[15];
  const float* bo   = (const float*)d_in[16];
  float* out = (float*)d_out;

  // workspace (~155 MB). Overlay timeline (all same-stream, serial):
  //  region A (67108864, 16.7M): qh (normrope..sparse) -> VT (trans_v..local)
  //  region B (83886080, 16.7M): hbf (prep..lklv-gemm) -> hidh (splitq..qgemm) -> merged (local..out-gemm)
  //  region C (100663296,16.7M): bt_lklv (prep..lklv-gemm) -> hidl (splitq..qgemm) -> sp (sparse..local)
  //  region D (137954304,16.7M): wqh|wql (splitq..qgemm) -> ql (normrope..sparse)
  char* ws = (char*)d_ws;
  float*    qf       = (float*)   (ws);                  // 33,554,432
  bf16*     lklv     = (bf16*)    (ws + 33554432);       // 33,554,432
  _Float16* qh       = (_Float16*)(ws + 67108864);       // region A
  bf16*     VT       = (bf16*)    (ws + 67108864);       // region A overlay
  bf16*     hbf      = (bf16*)    (ws + 83886080);       // region B
  _Float16* hidh     = (_Float16*)(ws + 83886080);       // region B overlay
  bf16*     merged   = (bf16*)    (ws + 83886080);       // region B overlay
  bf16*     bt_lklv  = (bf16*)    (ws + 100663296);      // region C
  _Float16* hidl     = (_Float16*)(ws + 100663296);      // region C overlay
  bf16*     sp       = (bf16*)    (ws + 100663296);      // region C overlay
  float*    WkvTs    = (float*)   (ws + 117440512);      //  2,097,152 (x1024)
  bf16*     WoT      = (bf16*)    (ws + 119537664);      //  8,388,608
  float*    entriesF = (float*)   (ws + 127926272);      //  8,388,608
  float*    ckvF     = (float*)   (ws + 136314880);      //  1,048,576
  _Float16* ckh      = (_Float16*)(ws + 137363456);      //    262,144
  _Float16* ckl      = (_Float16*)(ws + 137625600);      //    262,144
  float*    wlog     = (float*)   (ws + 137887744);      //     16,384
  float*    wsm      = (float*)   (ws + 137904128);      //     16,384
  float*    bQ       = (float*)   (ws + 137920512);      //      8,192
  float*    bLKLV    = (float*)   (ws + 137928704);      //     16,384
  float*    bKV      = (float*)   (ws + 137945088);      //      1,024
  float*    bO       = (float*)   (ws + 137946112);      //      8,192
  _Float16* wqh      = (_Float16*)(ws + 137954304);      // region D (8,388,608)
  _Float16* wql      = (_Float16*)(ws + 146342912);      // region D (8,388,608)
  _Float16* ql       = (_Float16*)(ws + 137954304);      // region D overlay (16.7M)

  // 1) all independent preprocessing in one launch
  prep_fused<<<dim3(12416), dim3(256), 0, stream>>>(hidden, hbf, Wlk, Wlv, Wo, bt_lklv, WoT,
                                                    Wk, Wv, WkvTs, Wcmp, bcmp, wlog,
                                                    bq, blk, blv, bk, bv, bo, bQ, bLKLV, bKV, bO);
  // 2) compress softmax (needs wlog)
  wsm_k<<<dim3(4), dim3(256), 0, stream>>>(wlog, wsm);
  // 3) lklv GEMM + entries (both ready; entries hides under the GEMM)
  lklv_entries_fused<<<dim3(9216), dim3(256), 0, stream>>>(hbf, bt_lklv, bLKLV, lklv,
                                                           hidden, wsm, entriesF);
  // 4) q-operand splits (hidh/hidl overlay hbf/bt_lklv — must follow launch 3)
  splitq_fused<<<dim3(9216), dim3(256), 0, stream>>>(hidden, hidh, hidl, Wq, wqh, wql);
  // 5) precise q GEMM + precise ckv GEMM co-resident (kills the 16-block tail)
  qgemm_fused<<<dim3(528), dim3(256), 0, stream>>>(hidh, hidl, wqh, wql, bQ, qf,
                                                   entriesF, WkvTs, bKV, ckvF);
  // 6) all norms/ropes in one launch
  normrope_fused<<<dim3(8448), dim3(256), 0, stream>>>(qf, qn_w, qh, ql, ckvF, kn_w, ckh, ckl, lklv);
  // 7) sparse branch (reads qh/ql; must precede VT overlay)
  sparse_v9<<<dim3(512, 8), dim3(1024), 0, stream>>>(qh, ql, ckh, ckl, ckvF, sp);
  // 8) V transpose (overlays qh)
  trans_v_k<<<dim3(64, 32), dim3(256), 0, stream>>>(lklv, VT);
  // 9) local branch + merge
  local_mfma<<<dim3(128, 16), dim3(128), 0, stream>>>(qf, lklv, VT, sp, merged);
  // 10) output projection
  gemm_bt<float><<<dim3(16, 32), dim3(256), 0, stream>>>(merged, WoT, bO, out, S_LEN, HID_, HID_, HID_);
}

// Round 10
// 887.660 us; speedup vs baseline: 1.3743x; 1.1239x over previous
//
#include <hip/hip_runtime.h>
#include <hip/hip_bf16.h>
#include <hip/hip_fp16.h>
#include <stdint.h>

typedef __hip_bfloat16 bf16;
using bf16x8 = __attribute__((ext_vector_type(8))) short;     // 8 bf16
using half8  = __attribute__((ext_vector_type(8))) _Float16;  // 8 fp16
using f32x4  = __attribute__((ext_vector_type(4))) float;

#define S_LEN   4096
#define HID_    2048
#define NH_     16
#define D_      128
#define C_      1024
#define SCALE_  0.08838834764831845f   // 1/sqrt(128)
#define DESC_   (1.0 / 1048576.0)      // 2^-20 (undo ×1024 on both operands)

__device__ __forceinline__ void storeC(float* p, float v) { *p = v; }
__device__ __forceinline__ void storeC(bf16* p, float v)  { *p = __float2bfloat16(v); }
__device__ __forceinline__ void split2(float x, _Float16& h, _Float16& l) {
  h = (_Float16)x; l = (_Float16)(x - (float)h);
}
__device__ __forceinline__ short bf2s(bf16 b) { short s; __builtin_memcpy(&s, &b, 2); return s; }

#define GLDS(src, dst) __builtin_amdgcn_global_load_lds( \
    (const __attribute__((address_space(1))) void*)(src), \
    (__attribute__((address_space(3))) void*)(dst), 16, 0, 0)

// ================= device bodies (verbatim arithmetic) =================

__device__ __forceinline__ void cvt_bias_body(int bxx, const float* __restrict__ src, bf16* __restrict__ dst,
                                              const float* bq, const float* blk, const float* blv,
                                              const float* bk, const float* bv, const float* bo,
                                              float* bQ, float* bLKLV, float* bKV, float* bO) {
  int i = (bxx * 256 + threadIdx.x) * 4;
  float4 v = *(const float4*)(src + i);
  bf16 o[4] = {__float2bfloat16(v.x), __float2bfloat16(v.y),
               __float2bfloat16(v.z), __float2bfloat16(v.w)};
  *(uint2*)(dst + i) = *(uint2*)o;
  int ib = bxx * 256 + threadIdx.x;
  if (ib < 8448) {
    if (ib < 2048)      bQ[ib] = bq[ib];
    else if (ib < 6144) { int j = ib - 2048; bLKLV[j] = (j < 2048) ? blk[j] : blv[j - 2048]; }
    else if (ib < 6400) { int j = ib - 6144; bKV[j] = (j < 128) ? bk[j] : bv[j - 128]; }
    else                bO[ib - 6400] = bo[ib - 6400];
  }
}

__device__ __forceinline__ void transpose3_body(int bxx, int byy, int bzz, char* smem,
                                                const float* __restrict__ Wlk, const float* __restrict__ Wlv,
                                                const float* __restrict__ Wo,
                                                bf16* __restrict__ bt_lklv, bf16* __restrict__ WoT) {
  float (*tile)[65] = (float(*)[65])smem;
  const float* src = (bzz == 0) ? Wlk : (bzz == 1) ? Wlv : Wo;
  bf16* dst = (bzz == 0) ? bt_lklv
            : (bzz == 1) ? (bt_lklv + (size_t)2048 * HID_) : WoT;
  const int c0 = bxx * 64, r0 = byy * 64;
  const int t = threadIdx.x, cc = t & 63, rb = t >> 6;
#pragma unroll
  for (int i = 0; i < 16; ++i) {
    int r = rb + i * 4;
    tile[r][cc] = src[(size_t)(r0 + r) * HID_ + c0 + cc];
  }
  __syncthreads();
#pragma unroll
  for (int i = 0; i < 16; ++i) {
    int r = rb + i * 4;
    dst[(size_t)(c0 + r) * HID_ + r0 + cc] = __float2bfloat16(tile[cc][r]);
  }
}

__device__ __forceinline__ void trans_kv_body(int bxx, int byy, int bzz, char* smem,
                                              const float* __restrict__ Wk, const float* __restrict__ Wv,
                                              float* __restrict__ WkvTs) {
  float (*tile)[65] = (float(*)[65])smem;
  const float* src = bzz ? Wv : Wk;
  float* dst = WkvTs + (bzz ? (size_t)128 * HID_ : 0);
  const int c0 = bxx * 64, r0 = byy * 64;
  const int t = threadIdx.x, cc = t & 63, rb = t >> 6;
#pragma unroll
  for (int i = 0; i < 16; ++i) {
    int r = rb + i * 4;
    tile[r][cc] = src[(size_t)(r0 + r) * 128 + c0 + cc];
  }
  __syncthreads();
#pragma unroll
  for (int i = 0; i < 16; ++i) {
    int r = rb + i * 4;
    dst[(size_t)(c0 + r) * HID_ + r0 + cc] = tile[cc][r] * 1024.0f;
  }
}

__device__ __forceinline__ void wlog_body(int bxx, const float* __restrict__ hidden,
                                          const float* __restrict__ wcmp, const float* __restrict__ bcmp,
                                          float* __restrict__ wlog) {
  int s = bxx * 4 + (threadIdx.x >> 6);
  int lane = threadIdx.x & 63;
  const float* hp = hidden + (size_t)s * HID_;
  double acc = 0.0;
  for (int i = lane; i < HID_; i += 64)
    acc += (double)hp[i] * (double)wcmp[i];
#pragma unroll
  for (int m = 32; m; m >>= 1) acc += __shfl_xor(acc, m, 64);
  if (lane == 0) wlog[s] = (float)(acc + (double)bcmp[0]);
}

__device__ __forceinline__ void split_q_body(int bxx, const float* __restrict__ src,
                                             _Float16* __restrict__ oh, _Float16* __restrict__ ol) {
  int i = (bxx * 256 + threadIdx.x) * 4;
  float4 v = *(const float4*)(src + i);
  float xs[4] = {v.x, v.y, v.z, v.w};
  _Float16 hh[4], ll[4];
#pragma unroll
  for (int e = 0; e < 4; ++e) split2(xs[e] * 1024.0f, hh[e], ll[e]);
  *(uint2*)(oh + i) = *(uint2*)hh;
  *(uint2*)(ol + i) = *(uint2*)ll;
}

__device__ __forceinline__ void trans_split_wq_body(int bxx, int byy, char* smem,
                                                    const float* __restrict__ src,
                                                    _Float16* __restrict__ oh, _Float16* __restrict__ ol) {
  float (*tile)[65] = (float(*)[65])smem;
  const int c0 = bxx * 64, r0 = byy * 64;
  const int t = threadIdx.x, cc = t & 63, rb = t >> 6;
#pragma unroll
  for (int i = 0; i < 16; ++i) {
    int r = rb + i * 4;
    tile[r][cc] = src[(size_t)(r0 + r) * HID_ + c0 + cc];
  }
  __syncthreads();
#pragma unroll
  for (int i = 0; i < 16; ++i) {
    int r = rb + i * 4;
    float x = tile[cc][r] * 1024.0f;
    _Float16 h, l; split2(x, h, l);
    size_t off = (size_t)(c0 + r) * HID_ + r0 + cc;
    oh[off] = h; ol[off] = l;
  }
}

__device__ __forceinline__ void entries_body(int bxx, const float* __restrict__ hidden,
                                             const float* __restrict__ wsm, float* __restrict__ entriesF) {
  int idx = bxx * 256 + threadIdx.x;
  int c = idx >> 11, hcol = idx & 2047;
  double e = 0.0;
#pragma unroll
  for (int r = 0; r < 4; ++r)
    e += (double)wsm[4 * c + r] * (double)hidden[(size_t)(4 * c + r) * HID_ + hcol];
  entriesF[idx] = (float)e;
}

template <typename OutT>
__device__ __forceinline__ void gemm_bt_body(int bxp, int byp, bf16* As, bf16* Bs,
                                             const bf16* __restrict__ A, const bf16* __restrict__ BT,
                                             const float* __restrict__ bias, OutT* __restrict__ Cmat,
                                             int M, int N, int K, int lda) {
  const int t = threadIdx.x;
  const int wave = t >> 6, lane = t & 63;
  const int wr = wave >> 1, wc = wave & 1;
  const int quad = lane >> 4, l15 = lane & 15;
  const int bx = bxp * 128, by = byp * 128;
  const int srow = t >> 2, scol = (t & 3) * 8;
  f32x4 acc[4][4] = {};
  const bf16* a0 = A + (size_t)(by + srow) * lda + scol;
  const bf16* a1 = A + (size_t)(by + 64 + srow) * lda + scol;
  const bf16* b0 = BT + (size_t)(bx + srow) * K + scol;
  const bf16* b1 = BT + (size_t)(bx + 64 + srow) * K + scol;
  for (int k0 = 0; k0 < K; k0 += 32) {
    GLDS(a0 + k0, As + t * 8);
    GLDS(a1 + k0, As + 2048 + t * 8);
    GLDS(b0 + k0, Bs + t * 8);
    GLDS(b1 + k0, Bs + 2048 + t * 8);
    __syncthreads();
    bf16x8 aF[4], bF[4];
#pragma unroll
    for (int i = 0; i < 4; ++i)
      aF[i] = *(const bf16x8*)(As + (wr * 64 + i * 16 + l15) * 32 + quad * 8);
#pragma unroll
    for (int j = 0; j < 4; ++j)
      bF[j] = *(const bf16x8*)(Bs + (wc * 64 + j * 16 + l15) * 32 + quad * 8);
#pragma unroll
    for (int i = 0; i < 4; ++i)
#pragma unroll
      for (int j = 0; j < 4; ++j)
        acc[i][j] = __builtin_amdgcn_mfma_f32_16x16x32_bf16(aF[i], bF[j], acc[i][j], 0, 0, 0);
    __syncthreads();
  }
#pragma unroll
  for (int i = 0; i < 4; ++i)
#pragma unroll
    for (int j = 0; j < 4; ++j)
#pragma unroll
      for (int r = 0; r < 4; ++r) {
        int row = by + wr * 64 + i * 16 + quad * 4 + r;
        int col = bx + wc * 64 + j * 16 + l15;
        storeC(&Cmat[(size_t)row * N + col], acc[i][j][r] + bias[col]);
      }
}

// ---- precise q GEMM v2: 128x64 tile (2x grid -> 4 blocks/CU), XOR-swizzled staging ----
// Swizzle (rule #21 compliant): GLDS dest stays lane-linear; the global SOURCE column is
// pre-swizzled g^=(row>>1)&3 and reads apply the same XOR -> per-phase bank spread 4->8
// distinct banks (8-way -> 4-way). MFMA 4-chain order + per-kstep f64 accumulate verbatim
// -> bit-identical output per element.
__device__ __forceinline__ void gemm_hl4b_body(int bxp, int byp, _Float16* Ahs, _Float16* Als,
                                               _Float16* Bhs, _Float16* Bls,
                                               const _Float16* __restrict__ Ah, const _Float16* __restrict__ Al,
                                               const _Float16* __restrict__ Bh, const _Float16* __restrict__ Bl,
                                               const float* __restrict__ bias, float* __restrict__ Cmat,
                                               int N, int K, int lda) {
  const int t = threadIdx.x;
  const int wave = t >> 6, lane = t & 63;
  const int wr = wave >> 1, wc = wave & 1;
  const int quad = lane >> 4, l15 = lane & 15;
  const int bx = bxp * 64, by = byp * 128;
  const int rA0 = t >> 2;            // A rows 0..63   (chunk t)
  const int rA1 = rA0 + 64;          // A rows 64..127 (chunk t+256)
  const int g   = t & 3;
  const int gsA0 = g ^ ((rA0 >> 1) & 3);
  const int gsA1 = g ^ ((rA1 >> 1) & 3);
  const int swz  = (l15 >> 1) & 3;
  double acc[4][2][4] = {};
  const _Float16* a0h = Ah + (size_t)(by + rA0) * lda + gsA0 * 8;
  const _Float16* a1h = Ah + (size_t)(by + rA1) * lda + gsA1 * 8;
  const _Float16* a0l = Al + (size_t)(by + rA0) * lda + gsA0 * 8;
  const _Float16* a1l = Al + (size_t)(by + rA1) * lda + gsA1 * 8;
  const _Float16* b0h = Bh + (size_t)(bx + rA0) * K + gsA0 * 8;
  const _Float16* b0l = Bl + (size_t)(bx + rA0) * K + gsA0 * 8;
  for (int k0 = 0; k0 < K; k0 += 32) {
    GLDS(a0h + k0, Ahs + t * 8);
    GLDS(a1h + k0, Ahs + 2048 + t * 8);
    GLDS(a0l + k0, Als + t * 8);
    GLDS(a1l + k0, Als + 2048 + t * 8);
    GLDS(b0h + k0, Bhs + t * 8);
    GLDS(b0l + k0, Bls + t * 8);
    __syncthreads();
    half8 aFh[4], aFl[4], bFh[2], bFl[2];
#pragma unroll
    for (int i = 0; i < 4; ++i) {
      int ro = (wr * 64 + i * 16 + l15) * 32 + (quad ^ swz) * 8;
      aFh[i] = *(const half8*)(Ahs + ro);
      aFl[i] = *(const half8*)(Als + ro);
    }
#pragma unroll
    for (int j = 0; j < 2; ++j) {
      int ro = (wc * 32 + j * 16 + l15) * 32 + (quad ^ swz) * 8;
      bFh[j] = *(const half8*)(Bhs + ro);
      bFl[j] = *(const half8*)(Bls + ro);
    }
#pragma unroll
    for (int i = 0; i < 4; ++i)
#pragma unroll
      for (int j = 0; j < 2; ++j) {
        f32x4 tt = {0.f, 0.f, 0.f, 0.f};
        tt = __builtin_amdgcn_mfma_f32_16x16x32_f16(aFl[i], bFl[j], tt, 0, 0, 0);
        tt = __builtin_amdgcn_mfma_f32_16x16x32_f16(aFl[i], bFh[j], tt, 0, 0, 0);
        tt = __builtin_amdgcn_mfma_f32_16x16x32_f16(aFh[i], bFl[j], tt, 0, 0, 0);
        tt = __builtin_amdgcn_mfma_f32_16x16x32_f16(aFh[i], bFh[j], tt, 0, 0, 0);
#pragma unroll
        for (int r = 0; r < 4; ++r) acc[i][j][r] += (double)tt[r];
      }
    __syncthreads();
  }
#pragma unroll
  for (int i = 0; i < 4; ++i)
#pragma unroll
    for (int j = 0; j < 2; ++j)
#pragma unroll
      for (int r = 0; r < 4; ++r) {
        int row = by + wr * 64 + i * 16 + quad * 4 + r;
        int col = bx + wc * 32 + j * 16 + l15;
        Cmat[(size_t)row * N + col] = (float)(acc[i][j][r] * DESC_ + (double)bias[col]);
      }
}

__device__ __forceinline__ void gemm_prec4_body(int bxp, int byp, _Float16* Ah, _Float16* Al,
                                                _Float16* Bh, _Float16* Bl,
                                                const float* __restrict__ A, const float* __restrict__ BT,
                                                const float* __restrict__ bias, float* __restrict__ Cmat,
                                                int M, int N, int K, int lda) {
  const int t = threadIdx.x;
  const int wave = t >> 6, lane = t & 63;
  const int wr = wave >> 1, wc = wave & 1;
  const int quad = lane >> 4, l15 = lane & 15;
  const int bx = bxp * 128, by = byp * 128;
  double acc[4][4][4] = {};
  for (int k0 = 0; k0 < K; k0 += 32) {
#pragma unroll
    for (int it = 0; it < 4; ++it) {
      int sl = t + it * 256;
      int isB = sl >> 9, s2 = sl & 511, r = s2 >> 2, g = s2 & 3;
      const float* src = isB ? (BT + (size_t)(bx + r) * K + k0 + g * 8)
                             : (A  + (size_t)(by + r) * lda + k0 + g * 8);
      float4 u = ((const float4*)src)[0];
      float4 v = ((const float4*)src)[1];
      float xs[8] = {u.x, u.y, u.z, u.w, v.x, v.y, v.z, v.w};
      half8 hh, ll;
#pragma unroll
      for (int e = 0; e < 8; ++e) {
        float x = isB ? xs[e] : xs[e] * 1024.0f;
        _Float16 h, l; split2(x, h, l);
        hh[e] = h; ll[e] = l;
      }
      _Float16* dh = (isB ? Bh : Ah) + r * 32 + g * 8;
      _Float16* dl = (isB ? Bl : Al) + r * 32 + g * 8;
      *(half8*)dh = hh;
      *(half8*)dl = ll;
    }
    __syncthreads();
    half8 aFh[4], aFl[4], bFh[4], bFl[4];
#pragma unroll
    for (int i = 0; i < 4; ++i) {
      int ro = (wr * 64 + i * 16 + l15) * 32 + quad * 8;
      aFh[i] = *(const half8*)(Ah + ro);
      aFl[i] = *(const half8*)(Al + ro);
    }
#pragma unroll
    for (int j = 0; j < 4; ++j) {
      int ro = (wc * 64 + j * 16 + l15) * 32 + quad * 8;
      bFh[j] = *(const half8*)(Bh + ro);
      bFl[j] = *(const half8*)(Bl + ro);
    }
#pragma unroll
    for (int i = 0; i < 4; ++i)
#pragma unroll
      for (int j = 0; j < 4; ++j) {
        f32x4 tt = {0.f, 0.f, 0.f, 0.f};
        tt = __builtin_amdgcn_mfma_f32_16x16x32_f16(aFl[i], bFl[j], tt, 0, 0, 0);
        tt = __builtin_amdgcn_mfma_f32_16x16x32_f16(aFl[i], bFh[j], tt, 0, 0, 0);
        tt = __builtin_amdgcn_mfma_f32_16x16x32_f16(aFh[i], bFl[j], tt, 0, 0, 0);
        tt = __builtin_amdgcn_mfma_f32_16x16x32_f16(aFh[i], bFh[j], tt, 0, 0, 0);
#pragma unroll
        for (int r = 0; r < 4; ++r) acc[i][j][r] += (double)tt[r];
      }
    __syncthreads();
  }
#pragma unroll
  for (int i = 0; i < 4; ++i)
#pragma unroll
    for (int j = 0; j < 4; ++j)
#pragma unroll
      for (int r = 0; r < 4; ++r) {
        int row = by + wr * 64 + i * 16 + quad * 4 + r;
        int col = bx + wc * 64 + j * 16 + l15;
        Cmat[(size_t)row * N + col] = (float)(acc[i][j][r] * DESC_ + (double)bias[col]);
      }
}

__device__ __forceinline__ void normrope_q_body(int s, double* csd, double* snd,
                                                float* __restrict__ base, const float* __restrict__ w,
                                                _Float16* __restrict__ qh, _Float16* __restrict__ ql) {
  const int t = threadIdx.x, wv = t >> 6, lane = t & 63;
  if (t < 32) {
    float invf = 1.0f / (float)pow(10000.0, (double)t * (1.0 / 32.0));
    float angf = (float)s * invf;
    double ang = (double)angf;
    csd[t] = cos(ang);
    snd[t] = sin(ang);
  }
  __syncthreads();
  const int fi = lane & 31;
  float* ps = base + (size_t)s * HID_;
  for (int h = wv; h < 16; h += 4) {
    float* p = ps + h * 128;
    double x0 = (double)p[lane];
    double x1 = (double)p[lane + 64];
    double ss = x0 * x0 + x1 * x1;
#pragma unroll
    for (int m = 32; m; m >>= 1) ss += __shfl_xor(ss, m, 64);
    double rstd = 1.0 / sqrt(ss * (1.0 / 128.0) + 1e-6);
    double n0 = x0 * rstd * (double)w[lane];
    double n1 = x1 * rstd * (double)w[lane + 64];
    double other = __shfl_xor(n0, 32, 64);
    double cs = csd[fi], sn = snd[fi];
    double r0 = (lane < 32) ? (n0 * cs - other * sn) : (other * sn + n0 * cs);
    float f0 = (float)r0, f1 = (float)n1;
    p[lane] = f0;
    p[lane + 64] = f1;
    _Float16 h0, l0, h1, l1;
    split2(f0 * 1024.0f, h0, l0);
    split2(f1 * 1024.0f, h1, l1);
    size_t off = (size_t)s * HID_ + h * 128;
    qh[off + lane] = h0;       ql[off + lane] = l0;
    qh[off + 64 + lane] = h1;  ql[off + 64 + lane] = l1;
  }
}

__device__ __forceinline__ void normrope_ck_body(int bxx, float* __restrict__ base, const float* __restrict__ w,
                                                 _Float16* __restrict__ ckh, _Float16* __restrict__ ckl) {
  int row = bxx * 4 + (threadIdx.x >> 6);
  int lane = threadIdx.x & 63;
  float* p = base + (size_t)row * 256;
  double x0 = (double)p[lane];
  double x1 = (double)p[lane + 64];
  double ss = x0 * x0 + x1 * x1;
#pragma unroll
  for (int m = 32; m; m >>= 1) ss += __shfl_xor(ss, m, 64);
  double rstd = 1.0 / sqrt(ss * (1.0 / 128.0) + 1e-6);
  double n0 = x0 * rstd * (double)w[lane];
  double n1 = x1 * rstd * (double)w[lane + 64];
  double other = __shfl_xor(n0, 32, 64);
  int fi = lane & 31;
  float invf = 1.0f / (float)pow(10000.0, (double)fi * (1.0 / 32.0));
  float angf = (float)(row * 4 + 3) * invf;
  double ang = (double)angf;
  double cs = cos(ang), sn = sin(ang);
  double r0 = (lane < 32) ? (n0 * cs - other * sn) : (other * sn + n0 * cs);
  float f0 = (float)r0, f1 = (float)n1;
  p[lane] = f0;
  p[lane + 64] = f1;
  _Float16 h0, l0, h1, l1;
  split2(f0 * 1024.0f, h0, l0);
  split2(f1 * 1024.0f, h1, l1);
  ckh[row * 128 + lane] = h0;       ckl[row * 128 + lane] = l0;
  ckh[row * 128 + 64 + lane] = h1;  ckl[row * 128 + 64 + lane] = l1;
}

__device__ __forceinline__ void normrope_bfl_body(int s, float* csf, float* snf,
                                                  bf16* __restrict__ base, const float* __restrict__ w) {
  const int t = threadIdx.x, wv = t >> 6, lane = t & 63;
  if (t < 32) {
    float invf = 1.0f / (float)pow(10000.0, (double)t * (1.0 / 32.0));
    float ang = (float)s * invf;
    csf[t] = cosf(ang);
    snf[t] = sinf(ang);
  }
  __syncthreads();
  const int fi = lane & 31;
  bf16* ps = base + (size_t)s * 4096;
  for (int h = wv; h < 16; h += 4) {
    bf16* p = ps + h * 128;
    float x0 = __bfloat162float(p[lane]);
    float x1 = __bfloat162float(p[lane + 64]);
    float ss = x0 * x0 + x1 * x1;
#pragma unroll
    for (int m = 32; m; m >>= 1) ss += __shfl_xor(ss, m, 64);
    float rstd = rsqrtf(ss * 0.0078125f + 1e-6f);
    float n0 = x0 * rstd * w[lane];
    float n1 = x1 * rstd * w[lane + 64];
    float other = __shfl_xor(n0, 32, 64);
    float cs = csf[fi], sn = snf[fi];
    float r0 = (lane < 32) ? (n0 * cs - other * sn) : (other * sn + n0 * cs);
    p[lane] = __float2bfloat16(r0);
    p[lane + 64] = __float2bfloat16(n1);
  }
}

// ================= fused launches =================

// [transpose3: 0..3071][kv: 3072..3199][cvt_bias: 3200..11391][wlog: 11392..12415]
__global__ __launch_bounds__(256) void prep_fused(const float* hidden, bf16* hbf,
                                                  const float* Wlk, const float* Wlv, const float* Wo,
                                                  bf16* bt_lklv, bf16* WoT,
                                                  const float* Wk, const float* Wv, float* WkvTs,
                                                  const float* wcmp, const float* bcmp, float* wlog,
                                                  const float* bq, const float* blk, const float* blv,
                                                  const float* bk, const float* bv, const float* bo,
                                                  float* bQ, float* bLKLV, float* bKV, float* bO) {
  __shared__ __align__(16) char smem[16640];
  int b = blockIdx.x;
  if (b < 3072) {
    int z = b >> 10, rem = b & 1023;
    transpose3_body(rem & 31, rem >> 5, z, smem, Wlk, Wlv, Wo, bt_lklv, WoT);
  } else if (b < 3200) {
    int tt = b - 3072;
    trans_kv_body(tt & 1, (tt & 63) >> 1, tt >> 6, smem, Wk, Wv, WkvTs);
  } else if (b < 11392) {
    cvt_bias_body(b - 3200, hidden, hbf, bq, blk, blv, bk, bv, bo, bQ, bLKLV, bKV, bO);
  } else {
    wlog_body(b - 11392, hidden, wcmp, bcmp, wlog);
  }
}

__global__ void wsm_k(const float* __restrict__ wlog, float* __restrict__ wsm) {
  int c = blockIdx.x * 256 + threadIdx.x;
  if (c >= C_) return;
  double v[4], m = -1e300;
#pragma unroll
  for (int r = 0; r < 4; ++r) { v[r] = (double)wlog[4 * c + r]; if (v[r] > m) m = v[r]; }
  double sum = 0.0;
#pragma unroll
  for (int r = 0; r < 4; ++r) { v[r] = exp(v[r] - m); sum += v[r]; }
#pragma unroll
  for (int r = 0; r < 4; ++r) wsm[4 * c + r] = (float)(v[r] / sum);
}

// [gemm_bt lklv: 0..1023][entries: 1024..9215]
__global__ __launch_bounds__(256) void lklv_entries_fused(const bf16* hbf, const bf16* bt_lklv,
                                                          const float* bLKLV, bf16* lklv,
                                                          const float* hidden, const float* wsm,
                                                          float* entriesF) {
  __shared__ __align__(16) bf16 AsBs[2][4096];
  int b = blockIdx.x;
  if (b < 1024) {
    gemm_bt_body<bf16>(b & 31, b >> 5, AsBs[0], AsBs[1], hbf, bt_lklv, bLKLV, lklv,
                       S_LEN, 4096, HID_, HID_);
  } else {
    entries_body(b - 1024, hidden, wsm, entriesF);
  }
}

// [trans_split_wq: 0..1023][split_q: 1024..9215]
__global__ __launch_bounds__(256) void splitq_fused(const float* hidden, _Float16* hidh, _Float16* hidl,
                                                    const float* Wq, _Float16* wqh, _Float16* wql) {
  __shared__ __align__(16) char smem[16640];
  int b = blockIdx.x;
  if (b < 1024) {
    trans_split_wq_body(b & 31, b >> 5, smem, Wq, wqh, wql);
  } else {
    split_q_body(b - 1024, hidden, hidh, hidl);
  }
}

// [gemm_prec4 ckv FIRST: 0..15 (runs concurrent, no tail)][gemm_hl4b: 16..1039]
__global__ __launch_bounds__(256) void qgemm_fused(const _Float16* hidh, const _Float16* hidl,
                                                   const _Float16* wqh, const _Float16* wql,
                                                   const float* bQ, float* qf,
                                                   const float* entriesF, const float* WkvTs,
                                                   const float* bKV, float* ckvF) {
  __shared__ __align__(16) _Float16 SH4[4][4096];
  int b = blockIdx.x;
  if (b < 16) {
    gemm_prec4_body(b & 1, b >> 1, SH4[0], SH4[1], SH4[2], SH4[3],
                    entriesF, WkvTs, bKV, ckvF, C_, 256, HID_, HID_);
  } else {
    int bb = b - 16;   // 1024 blocks: 32 N-tiles (64) x 32 M-tiles (128)
    gemm_hl4b_body(bb & 31, bb >> 5, SH4[0], SH4[1], SH4[2], SH4[3],
                   hidh, hidl, wqh, wql, bQ, qf, HID_, HID_, HID_);
  }
}

// [normrope_ck: 0..255][normrope_q: 256..4351][normrope_bfl: 4352..8447]
__global__ __launch_bounds__(256) void normrope_fused(float* qf, const float* qn_w,
                                                      _Float16* qh, _Float16* ql,
                                                      float* ckvF, const float* kn_w,
                                                      _Float16* ckh, _Float16* ckl,
                                                      bf16* lklv) {
  __shared__ double csd[32], snd[32];
  __shared__ float csf[32], snf[32];
  int b = blockIdx.x;
  if (b < 256) {
    normrope_ck_body(b, ckvF, kn_w, ckh, ckl);
  } else if (b < 4352) {
    normrope_q_body(b - 256, csd, snd, qf, qn_w, qh, ql);
  } else {
    normrope_bfl_body(b - 4352, csf, snf, lklv, kn_w);
  }
}

// ---------------- transpose lv half of lklv -> VT [2048][4096] ----------------
__global__ __launch_bounds__(256) void trans_v_k(const bf16* __restrict__ lklv, bf16* __restrict__ VT) {
  __shared__ ushort tile[64][65];
  const int s0 = blockIdx.x * 64, c0 = blockIdx.y * 64;
  const int t = threadIdx.x, cc = t & 63, rb = t >> 6;
  const ushort* src = (const ushort*)lklv;
#pragma unroll
  for (int i = 0; i < 16; ++i) {
    int r = rb + i * 4;
    tile[r][cc] = src[(size_t)(s0 + r) * 4096 + 2048 + c0 + cc];
  }
  __syncthreads();
  ushort* dst = (ushort*)VT;
#pragma unroll
  for (int i = 0; i < 16; ++i) {
    int r = rb + i * 4;
    dst[(size_t)(c0 + r) * 4096 + s0 + cc] = tile[cc][r];
  }
}

// ---------------- out projection (standalone gemm_bt wrapper) ----------------
template <typename OutT>
__global__ __launch_bounds__(256) void gemm_bt(const bf16* __restrict__ A, const bf16* __restrict__ BT,
                                               const float* __restrict__ bias, OutT* __restrict__ Cmat,
                                               int M, int N, int K, int lda) {
  __shared__ __align__(16) bf16 AsBs[2][4096];
  gemm_bt_body<OutT>(blockIdx.x, blockIdx.y, AsBs[0], AsBs[1], A, BT, bias, Cmat, M, N, K, lda);
}

// ---------------- sparse v9 (verbatim) ----------------
__global__ __launch_bounds__(1024, 8) void sparse_v9(const _Float16* __restrict__ qh, const _Float16* __restrict__ ql,
                                                     const _Float16* __restrict__ ckh, const _Float16* __restrict__ ckl,
                                                     const float* __restrict__ ckvF, bf16* __restrict__ sp) {
  __shared__ float sc[16 * 1024];               // 64 KB -> 2 blocks/CU
  const int by = blockIdx.y;
  const int s0 = blockIdx.x * 8;
  const int t = threadIdx.x, w = t >> 6, lane = t & 63;
  const int quad = lane >> 4, l15 = lane & 15;
  const int nvmax  = (s0 >> 2) + 2;
  const int ntiles = (nvmax + 15) >> 4;
  const double esc = (double)SCALE_ * DESC_;

  if (w < ntiles) {
    const int sA = s0 + (l15 & 7);
    const int hA = 2 * by + (l15 >> 3);
    half8 aFh[4], aFl[4];
    {
      const _Float16* qbh = qh + (size_t)sA * HID_ + hA * 128 + quad * 8;
      const _Float16* qbl = ql + (size_t)sA * HID_ + hA * 128 + quad * 8;
#pragma unroll
      for (int kk = 0; kk < 4; ++kk) {
        aFh[kk] = *(const half8*)(qbh + kk * 32);
        aFl[kk] = *(const half8*)(qbl + kk * 32);
      }
    }
    for (int ct = w; ct < ntiles; ct += 16) {
      const int c0 = ct * 16;
      const _Float16* kbh = ckh + (size_t)(c0 + l15) * 128 + quad * 8;
      const _Float16* kbl = ckl + (size_t)(c0 + l15) * 128 + quad * 8;
      double a64[4] = {0.0, 0.0, 0.0, 0.0};
#pragma unroll
      for (int kk = 0; kk < 4; ++kk) {
        half8 bh = *(const half8*)(kbh + kk * 32);
        half8 bl = *(const half8*)(kbl + kk * 32);
        f32x4 tt = {0.f, 0.f, 0.f, 0.f};
        tt = __builtin_amdgcn_mfma_f32_16x16x32_f16(aFl[kk], bl, tt, 0, 0, 0);
        tt = __builtin_amdgcn_mfma_f32_16x16x32_f16(aFl[kk], bh, tt, 0, 0, 0);
        tt = __builtin_amdgcn_mfma_f32_16x16x32_f16(aFh[kk], bl, tt, 0, 0, 0);
        tt = __builtin_amdgcn_mfma_f32_16x16x32_f16(aFh[kk], bh, tt, 0, 0, 0);
#pragma unroll
        for (int r = 0; r < 4; ++r) a64[r] += (double)tt[r];
      }
#pragma unroll
      for (int r = 0; r < 4; ++r)
        sc[(quad * 4 + r) * 1024 + c0 + l15] = (float)(a64[r] * esc);
    }
  }
  __syncthreads();
  if (w >= 4) return;

  const int q = w * 4 + quad;
  const int p2 = q >> 3, wq = q & 7;
  const int s = s0 + wq;
  const int nv = (s >= 3) ? (((s - 3) >> 2) + 1) : 0;
  const float* srow = sc + q * 1024;
  const int jmaxB = (nvmax + 63) >> 6;

  float tv0 = -1e38f, tv1 = -1e38f, tv2 = -1e38f, tv3 = -1e38f;
  int   ti0 = 0x40000000, ti1 = 0x40000000, ti2 = 0x40000000, ti3 = 0x40000000;
  for (int j = 0; j < jmaxB; ++j) {
    int cb = j * 64 + l15 * 4;
    float4 vv = *(const float4*)(srow + cb);
    float xs[4] = {vv.x, vv.y, vv.z, vv.w};
#pragma unroll
    for (int e = 0; e < 4; ++e) {
      int c = cb + e;
      float v = (c < nv) ? xs[e] : -1e38f;
      if (v > tv3) {
        if (v > tv0)      { tv3=tv2;ti3=ti2; tv2=tv1;ti2=ti1; tv1=tv0;ti1=ti0; tv0=v;ti0=c; }
        else if (v > tv1) { tv3=tv2;ti3=ti2; tv2=tv1;ti2=ti1; tv1=v;ti1=c; }
        else if (v > tv2) { tv3=tv2;ti3=ti2; tv2=v;ti2=c; }
        else              { tv3=v;ti3=c; }
      }
    }
  }

  unsigned long long deadm = 0ull;
  int ncons = 0;
  float bvs[8]; int bis[8];
#pragma unroll
  for (int it = 0; it < 8; ++it) {
    float bv = tv0; int bi = ti0;
#pragma unroll
    for (int mm = 1; mm <= 8; mm <<= 1) {
      float ov = __shfl_xor(bv, mm, 64);
      int   oi = __shfl_xor(bi, mm, 64);
      if (ov > bv || (ov == bv && oi < bi)) { bv = ov; bi = oi; }
    }
    bvs[it] = bv; bis[it] = bi;
    if (bv > -1e29f && (((bi >> 2) & 15) == l15)) {
      deadm |= 1ull << (((bi >> 6) << 2) | (bi & 3));
      tv0=tv1;ti0=ti1; tv1=tv2;ti1=ti2; tv2=tv3;ti2=ti3;
      tv3=-1e38f; ti3=0x40000000;
      if (++ncons == 4) {
        ncons = 0;
        tv0=tv1=tv2=tv3=-1e38f;
        ti0=ti1=ti2=ti3=0x40000000;
        for (int j = 0; j < jmaxB; ++j) {
          int cb = j * 64 + l15 * 4;
          float4 vv = *(const float4*)(srow + cb);
          float xs[4] = {vv.x, vv.y, vv.z, vv.w};
#pragma unroll
          for (int e = 0; e < 4; ++e) {
            int c = cb + e;
            int li = ((c >> 6) << 2) | (c & 3);
            float v = (c < nv && !((deadm >> li) & 1ull)) ? xs[e] : -1e38f;
            if (v > tv3) {
              if (v > tv0)      { tv3=tv2;ti3=ti2; tv2=tv1;ti2=ti1; tv1=tv0;ti1=ti0; tv0=v;ti0=c; }
              else if (v > tv1) { tv3=tv2;ti3=ti2; tv2=tv1;ti2=ti1; tv1=v;ti1=c; }
              else if (v > tv2) { tv3=tv2;ti3=ti2; tv2=v;ti2=c; }
              else              { tv3=v;ti3=c; }
            }
          }
        }
      }
    }
  }

  const float m0 = bvs[0];
  float a0=0.f,a1=0.f,a2=0.f,a3=0.f,a4=0.f,a5=0.f,a6=0.f,a7=0.f;
  float esum = 0.f;
#pragma unroll
  for (int it = 0; it < 8; ++it) {
    if (bvs[it] > -1e29f) {
      float wgt = expf(bvs[it] - m0);
      esum += wgt;
      const float* cvp = ckvF + (size_t)bis[it] * 256 + 128 + l15 * 8;
      float4 u = *(const float4*)cvp;
      float4 v = *(const float4*)(cvp + 4);
      a0 += wgt*u.x; a1 += wgt*u.y; a2 += wgt*u.z; a3 += wgt*u.w;
      a4 += wgt*v.x; a5 += wgt*v.y; a6 += wgt*v.z; a7 += wgt*v.w;
    }
  }
  float inv = 1.0f / fmaxf(esum, 1e-9f);
  bf16* op = sp + (size_t)s * 2048 + (2 * by + p2) * 128 + l15 * 8;
  bf16 ob[8] = {__float2bfloat16(a0*inv), __float2bfloat16(a1*inv),
                __float2bfloat16(a2*inv), __float2bfloat16(a3*inv),
                __float2bfloat16(a4*inv), __float2bfloat16(a5*inv),
                __float2bfloat16(a6*inv), __float2bfloat16(a7*inv)};
  *(uint4*)op = *(uint4*)ob;
}

// ---------------- local sliding-window via MFMA (verbatim) ----------------
__global__ __launch_bounds__(128) void local_mfma(const float* __restrict__ qf,
                                                  const bf16* __restrict__ lklv,
                                                  const bf16* __restrict__ VT,
                                                  const bf16* __restrict__ sp,
                                                  bf16* __restrict__ merged) {
  constexpr int PADP = 168;
  __shared__ bf16 PhS[2][16 * PADP];
  __shared__ bf16 PlS[2][16 * PADP];
  const int h = blockIdx.y;
  const int t = threadIdx.x, w = t >> 6, lane = t & 63;
  const int quad = lane >> 4, l15 = lane & 15;
  const int sw = blockIdx.x * 32 + w * 16;
  const int kbase = sw - 128;
  const int ridx = quad * 4;

  bf16x8 qH[4], qL[4];
  {
    const float* qp = qf + (size_t)(sw + l15) * HID_ + h * 128 + quad * 8;
#pragma unroll
    for (int kk = 0; kk < 4; ++kk) {
      float4 u = *(const float4*)(qp + kk * 32);
      float4 v = *(const float4*)(qp + kk * 32 + 4);
      float xs[8] = {u.x, u.y, u.z, u.w, v.x, v.y, v.z, v.w};
      bf16x8 hh, ll;
#pragma unroll
      for (int e = 0; e < 8; ++e) {
        bf16 bh = __float2bfloat16(xs[e]);
        float fh = __bfloat162float(bh);
        bf16 bl = __float2bfloat16(xs[e] - fh);
        hh[e] = bf2s(bh); ll[e] = bf2s(bl);
      }
      qH[kk] = hh; qL[kk] = ll;
    }
  }

  float sc[9][4];
#pragma unroll
  for (int ct = 0; ct < 9; ++ct) {
    int key0 = kbase + ct * 16 + l15;
    const bf16* kp = lklv + (size_t)(key0 < 0 ? 0 : key0) * 4096 + h * 128 + quad * 8;
    f32x4 acc = {0.f, 0.f, 0.f, 0.f};
#pragma unroll
    for (int kk = 0; kk < 4; ++kk) {
      bf16x8 kb = *(const bf16x8*)(kp + kk * 32);
      acc = __builtin_amdgcn_mfma_f32_16x16x32_bf16(qL[kk], kb, acc, 0, 0, 0);
      acc = __builtin_amdgcn_mfma_f32_16x16x32_bf16(qH[kk], kb, acc, 0, 0, 0);
    }
#pragma unroll
    for (int r = 0; r < 4; ++r) sc[ct][r] = acc[r] * SCALE_;
  }

  float mrow[4] = {-1e30f, -1e30f, -1e30f, -1e30f};
#pragma unroll
  for (int ct = 0; ct < 9; ++ct) {
    int cidx = ct * 16 + l15;
#pragma unroll
    for (int r = 0; r < 4; ++r) {
      bool valid = (cidx >= ridx + r) && (cidx <= ridx + r + 128) && (kbase + cidx >= 0);
      float v = valid ? sc[ct][r] : -1e30f;
      sc[ct][r] = v;
      mrow[r] = fmaxf(mrow[r], v);
    }
  }
#pragma unroll
  for (int mm = 1; mm <= 8; mm <<= 1)
#pragma unroll
    for (int r = 0; r < 4; ++r) mrow[r] = fmaxf(mrow[r], __shfl_xor(mrow[r], mm, 64));

  bf16* phb = &PhS[w][0];
  bf16* plb = &PlS[w][0];
  for (int z = lane; z < 256; z += 64) {
    int zr = z >> 4, zc = z & 15;
    phb[zr * PADP + 144 + zc] = __float2bfloat16(0.f);
    plb[zr * PADP + 144 + zc] = __float2bfloat16(0.f);
  }
  float lsum[4] = {0.f, 0.f, 0.f, 0.f};
#pragma unroll
  for (int ct = 0; ct < 9; ++ct) {
    int cidx = ct * 16 + l15;
#pragma unroll
    for (int r = 0; r < 4; ++r) {
      float e = (sc[ct][r] > -1e29f) ? expf(sc[ct][r] - mrow[r]) : 0.f;
      lsum[r] += e;
      bf16 bh = __float2bfloat16(e);
      float fh = __bfloat162float(bh);
      bf16 bl = __float2bfloat16(e - fh);
      phb[(ridx + r) * PADP + cidx] = bh;
      plb[(ridx + r) * PADP + cidx] = bl;
    }
  }
#pragma unroll
  for (int mm = 1; mm <= 8; mm <<= 1)
#pragma unroll
    for (int r = 0; r < 4; ++r) lsum[r] += __shfl_xor(lsum[r], mm, 64);
  float inv[4];
#pragma unroll
  for (int r = 0; r < 4; ++r) inv[r] = 1.0f / lsum[r];

  bf16x8 pH[5], pL[5];
#pragma unroll
  for (int kk = 0; kk < 5; ++kk) {
    pH[kk] = *(const bf16x8*)(phb + l15 * PADP + kk * 32 + quad * 8);
    pL[kk] = *(const bf16x8*)(plb + l15 * PADP + kk * 32 + quad * 8);
  }

#pragma unroll
  for (int dt = 0; dt < 8; ++dt) {
    const bf16* vrow = VT + (size_t)(h * 128 + dt * 16 + l15) * 4096;
    f32x4 acc = {0.f, 0.f, 0.f, 0.f};
#pragma unroll
    for (int kk = 0; kk < 5; ++kk) {
      int ko = kbase + kk * 32 + quad * 8;
      ko = ko < 0 ? 0 : (ko > 4088 ? 4088 : ko);
      bf16x8 vb = *(const bf16x8*)(vrow + ko);
      acc = __builtin_amdgcn_mfma_f32_16x16x32_bf16(pL[kk], vb, acc, 0, 0, 0);
      acc = __builtin_amdgcn_mfma_f32_16x16x32_bf16(pH[kk], vb, acc, 0, 0, 0);
    }
#pragma unroll
    for (int r = 0; r < 4; ++r) {
      int srow = sw + ridx + r;
      size_t off = (size_t)srow * 2048 + h * 128 + dt * 16 + l15;
      float spv = __bfloat162float(sp[off]);
      merged[off] = __float2bfloat16((acc[r] * inv[r] + spv) * 0.5f);
    }
  }
}

// ---------------- host orchestration ----------------
extern "C" void kernel_launch(void* const* d_in, const int* in_sizes, int n_in,
                              void* d_out, int out_size, void* d_ws, size_t ws_size,
                              hipStream_t stream) {
  (void)in_sizes; (void)n_in; (void)out_size; (void)ws_size;
  const float* hidden = (const float*)d_in[0];
  const float* Wq   = (const float*)d_in[1];
  const float* bq   = (const float*)d_in[2];
  const float* Wcmp = (const float*)d_in[3];
  const float* bcmp = (const float*)d_in[4];
  const float* Wk   = (const float*)d_in[5];
  const float* bk   = (const float*)d_in[6];
  const float* Wv   = (const float*)d_in[7];
  const float* bv   = (const float*)d_in[8];
  const float* Wlk  = (const float*)d_in[9];
  const float* blk  = (const float*)d_in[10];
  const float* Wlv  = (const float*)d_in[11];
  const float* blv  = (const float*)d_in[12];
  const float* qn_w = (const float*)d_in[13];
  const float* kn_w = (const float*)d_in[14];
  const float* Wo   = (const float*)d_in[15];
  const float* bo   = (const float*)d_in[16];
  float* out = (float*)d_out;

  // workspace (~155 MB). Overlay timeline (all same-stream, serial):
  //  region A (67108864, 16.7M): qh (normrope..sparse) -> VT (trans_v..local)
  //  region B (83886080, 16.7M): hbf (prep..lklv-gemm) -> hidh (splitq..qgemm) -> merged (local..out-gemm)
  //  region C (100663296,16.7M): bt_lklv (prep..lklv-gemm) -> hidl (splitq..qgemm) -> sp (sparse..local)
  //  region D (137954304,16.7M): wqh|wql (splitq..qgemm) -> ql (normrope..sparse)
  char* ws = (char*)d_ws;
  float*    qf       = (float*)   (ws);                  // 33,554,432
  bf16*     lklv     = (bf16*)    (ws + 33554432);       // 33,554,432
  _Float16* qh       = (_Float16*)(ws + 67108864);       // region A
  bf16*     VT       = (bf16*)    (ws + 67108864);       // region A overlay
  bf16*     hbf      = (bf16*)    (ws + 83886080);       // region B
  _Float16* hidh     = (_Float16*)(ws + 83886080);       // region B overlay
  bf16*     merged   = (bf16*)    (ws + 83886080);       // region B overlay
  bf16*     bt_lklv  = (bf16*)    (ws + 100663296);      // region C
  _Float16* hidl     = (_Float16*)(ws + 100663296);      // region C overlay
  bf16*     sp       = (bf16*)    (ws + 100663296);      // region C overlay
  float*    WkvTs    = (float*)   (ws + 117440512);      //  2,097,152 (x1024)
  bf16*     WoT      = (bf16*)    (ws + 119537664);      //  8,388,608
  float*    entriesF = (float*)   (ws + 127926272);      //  8,388,608
  float*    ckvF     = (float*)   (ws + 136314880);      //  1,048,576
  _Float16* ckh      = (_Float16*)(ws + 137363456);      //    262,144
  _Float16* ckl      = (_Float16*)(ws + 137625600);      //    262,144
  float*    wlog     = (float*)   (ws + 137887744);      //     16,384
  float*    wsm      = (float*)   (ws + 137904128);      //     16,384
  float*    bQ       = (float*)   (ws + 137920512);      //      8,192
  float*    bLKLV    = (float*)   (ws + 137928704);      //     16,384
  float*    bKV      = (float*)   (ws + 137945088);      //      1,024
  float*    bO       = (float*)   (ws + 137946112);      //      8,192
  _Float16* wqh      = (_Float16*)(ws + 137954304);      // region D (8,388,608)
  _Float16* wql      = (_Float16*)(ws + 146342912);      // region D (8,388,608)
  _Float16* ql       = (_Float16*)(ws + 137954304);      // region D overlay (16.7M)

  // 1) all independent preprocessing in one launch
  prep_fused<<<dim3(12416), dim3(256), 0, stream>>>(hidden, hbf, Wlk, Wlv, Wo, bt_lklv, WoT,
                                                    Wk, Wv, WkvTs, Wcmp, bcmp, wlog,
                                                    bq, blk, blv, bk, bv, bo, bQ, bLKLV, bKV, bO);
  // 2) compress softmax (needs wlog)
  wsm_k<<<dim3(4), dim3(256), 0, stream>>>(wlog, wsm);
  // 3) lklv GEMM + entries (both ready; entries hides under the GEMM)
  lklv_entries_fused<<<dim3(9216), dim3(256), 0, stream>>>(hbf, bt_lklv, bLKLV, lklv,
                                                           hidden, wsm, entriesF);
  // 4) q-operand splits (hidh/hidl overlay hbf/bt_lklv — must follow launch 3)
  splitq_fused<<<dim3(9216), dim3(256), 0, stream>>>(hidden, hidh, hidl, Wq, wqh, wql);
  // 5) precise q GEMM (128x64 tiles, 1024 blocks) + ckv GEMM first (concurrent, no tail)
  qgemm_fused<<<dim3(1040), dim3(256), 0, stream>>>(hidh, hidl, wqh, wql, bQ, qf,
                                                    entriesF, WkvTs, bKV, ckvF);
  // 6) all norms/ropes in one launch
  normrope_fused<<<dim3(8448), dim3(256), 0, stream>>>(qf, qn_w, qh, ql, ckvF, kn_w, ckh, ckl, lklv);
  // 7) sparse branch (reads qh/ql; must precede VT overlay)
  sparse_v9<<<dim3(512, 8), dim3(1024), 0, stream>>>(qh, ql, ckh, ckl, ckvF, sp);
  // 8) V transpose (overlays qh)
  trans_v_k<<<dim3(64, 32), dim3(256), 0, stream>>>(lklv, VT);
  // 9) local branch + merge
  local_mfma<<<dim3(128, 16), dim3(128), 0, stream>>>(qf, lklv, VT, sp, merged);
  // 10) output projection
  gemm_bt<float><<<dim3(16, 32), dim3(256), 0, stream>>>(merged, WoT, bO, out, S_LEN, HID_, HID_, HID_);
}